// Round 4
// baseline (1374.958 us; speedup 1.0000x reference)
//
#include <hip/hip_runtime.h>
#include <cmath>

#define B_ 8
#define T_ 2048
#define BT_ 16384
#define D_ 512
#define H_ 1536
#define CM_ 192
#define KE_ 1344      // im2col K = 192*7
#define NFFT_ 1024
#define NF_ 513
#define HOP_ 256
#define NO2_ 1026
#define NPAD_ 1152    // head N padded to tile multiple
#define KI_ 1088      // ISTFT K (= 1026 padded to 64-multiple)
#define LOUT_ 524032

typedef _Float16 f16;
typedef f16 f16x8 __attribute__((ext_vector_type(8)));
typedef float f32x4 __attribute__((ext_vector_type(4)));
typedef float f32x16 __attribute__((ext_vector_type(16)));

__device__ __forceinline__ float gelu_f(float v) {
    return 0.5f * v * (1.0f + erff(v * 0.70710678118654752f));
}

__device__ __forceinline__ void gload16(const void* g, void* s) {
    __builtin_amdgcn_global_load_lds((const __attribute__((address_space(1))) void*)g,
                                     (__attribute__((address_space(3))) void*)s, 16, 0, 0);
}

// ---------------- conversion / prep kernels ----------------

__global__ __launch_bounds__(256) void k_cvt(const float* __restrict__ src,
                                             f16* __restrict__ dst, int n) {
    int i = blockIdx.x * 256 + threadIdx.x;
    if (i < n) dst[i] = (f16)src[i];
}

// head weights (1026,512) -> fp16 (1152,512) zero-padded rows
__global__ __launch_bounds__(256) void k_cvt_head(const float* __restrict__ src,
                                                  f16* __restrict__ dst) {
    int i = blockIdx.x * 256 + threadIdx.x;
    if (i >= NPAD_ * D_) return;
    int row = i >> 9;
    dst[i] = (row < NO2_) ? (f16)src[i] : (f16)0.0f;
}

__global__ __launch_bounds__(256) void k_pad_hb(const float* __restrict__ src,
                                                float* __restrict__ dst) {
    int i = blockIdx.x * 256 + threadIdx.x;
    if (i < NPAD_) dst[i] = (i < NO2_) ? src[i] : 0.0f;
}

// dw (8,512,7) -> dwT[bl][k][d]
__global__ __launch_bounds__(256) void k_cvtdw(const float* __restrict__ dw,
                                               float* __restrict__ dwT) {
    int i = blockIdx.x * 256 + threadIdx.x;
    if (i >= 8 * 7 * 512) return;
    int bl = i / 3584;
    int rem = i - bl * 3584;
    int k = rem >> 9;
    int d = rem & 511;
    dwT[i] = dw[bl * 3584 + d * 7 + k];
}

// ISTFT basis fp16: wmat[n][f2], f2<513: cos*scale ; 513..1025: -sin*scale ; pad 0
__global__ __launch_bounds__(256) void k_build_wmat(f16* __restrict__ wmat) {
    int idx = blockIdx.x * 256 + threadIdx.x;
    if (idx >= NFFT_ * KI_) return;
    int n = idx / KI_;
    int f2 = idx - n * KI_;
    float v = 0.0f;
    if (f2 < NF_) {
        int r = (n * f2) & (NFFT_ - 1);
        float sc = (f2 == 0 || f2 == NF_ - 1) ? (1.0f / NFFT_) : (2.0f / NFFT_);
        v = cospif((float)r * (2.0f / NFFT_)) * sc;
    } else if (f2 < NO2_) {
        int f = f2 - NF_;
        int r = (n * f) & (NFFT_ - 1);
        float sc = (f == 0 || f == NF_ - 1) ? (1.0f / NFFT_) : (2.0f / NFFT_);
        v = -sinpif((float)r * (2.0f / NFFT_)) * sc;
    }
    wmat[idx] = (f16)v;
}

// im2col for embed conv: A[bt][c*7+k] = mel[b][c][t+k-3]
__global__ __launch_bounds__(256) void k_im2col(const float* __restrict__ mel,
                                                f16* __restrict__ A) {
    int idx = blockIdx.x * 256 + threadIdx.x;
    if (idx >= BT_ * KE_) return;
    int bt = idx / KE_;
    int ck = idx - bt * KE_;
    int c = ck / 7;
    int kk = ck - c * 7;
    int b = bt >> 11;
    int t = bt & (T_ - 1);
    int tt = t + kk - 3;
    float v = (tt >= 0 && tt < T_) ? mel[((size_t)b * CM_ + c) * T_ + tt] : 0.0f;
    A[idx] = (f16)v;
}

// ---------------- LayerNorm over D=512, one wave per row ----------------
template <bool HOUT>
__global__ __launch_bounds__(64) void k_ln(const float* __restrict__ in,
                                           void* __restrict__ out,
                                           const float* __restrict__ w,
                                           const float* __restrict__ b) {
    int row = blockIdx.x;
    int lane = threadIdx.x;
    const float* p = in + (size_t)row * D_ + lane * 8;
    float4 v0 = *(const float4*)p;
    float4 v1 = *(const float4*)(p + 4);
    float s  = v0.x + v0.y + v0.z + v0.w + v1.x + v1.y + v1.z + v1.w;
    float ss = v0.x * v0.x + v0.y * v0.y + v0.z * v0.z + v0.w * v0.w +
               v1.x * v1.x + v1.y * v1.y + v1.z * v1.z + v1.w * v1.w;
#pragma unroll
    for (int off = 32; off > 0; off >>= 1) {
        s  += __shfl_xor(s, off);
        ss += __shfl_xor(ss, off);
    }
    float mean = s * (1.0f / 512.0f);
    float var  = ss * (1.0f / 512.0f) - mean * mean;
    float rs = rsqrtf(var + 1e-5f);
    const float* wp = w + lane * 8;
    const float* bp = b + lane * 8;
    float4 w0 = *(const float4*)wp, w1 = *(const float4*)(wp + 4);
    float4 b0 = *(const float4*)bp, b1 = *(const float4*)(bp + 4);
    float o[8];
    o[0] = (v0.x - mean) * rs * w0.x + b0.x;
    o[1] = (v0.y - mean) * rs * w0.y + b0.y;
    o[2] = (v0.z - mean) * rs * w0.z + b0.z;
    o[3] = (v0.w - mean) * rs * w0.w + b0.w;
    o[4] = (v1.x - mean) * rs * w1.x + b1.x;
    o[5] = (v1.y - mean) * rs * w1.y + b1.y;
    o[6] = (v1.z - mean) * rs * w1.z + b1.z;
    o[7] = (v1.w - mean) * rs * w1.w + b1.w;
    if constexpr (HOUT) {
        f16x8 h;
#pragma unroll
        for (int i = 0; i < 8; ++i) h[i] = (f16)o[i];
        *(f16x8*)((f16*)out + (size_t)row * D_ + lane * 8) = h;
    } else {
        float* q = (float*)out + (size_t)row * D_ + lane * 8;
        *(float4*)q = make_float4(o[0], o[1], o[2], o[3]);
        *(float4*)(q + 4) = make_float4(o[4], o[5], o[6], o[7]);
    }
}

// ---------------- fused depthwise conv (k=7 over t) + LayerNorm -> fp16 ----------------
__global__ __launch_bounds__(64) void k_dwln(const float* __restrict__ x,
                                             const float* __restrict__ dwT,
                                             const float* __restrict__ db,
                                             const float* __restrict__ nw,
                                             const float* __restrict__ nb,
                                             f16* __restrict__ out) {
    int bt = blockIdx.x;
    int t = bt & (T_ - 1);
    int base = bt - t;
    int lane = threadIdx.x;
    int d0 = lane << 3;
    float a[8];
    *(float4*)&a[0] = *(const float4*)(db + d0);
    *(float4*)&a[4] = *(const float4*)(db + d0 + 4);
#pragma unroll
    for (int k = 0; k < 7; ++k) {
        int tt = t + k - 3;
        if (tt < 0 || tt >= T_) continue;
        const float* xp = x + (((size_t)(base + tt)) << 9) + d0;
        float4 x0 = *(const float4*)xp, x1 = *(const float4*)(xp + 4);
        const float* wp = dwT + (k << 9) + d0;
        float4 w0 = *(const float4*)wp, w1 = *(const float4*)(wp + 4);
        a[0] = fmaf(w0.x, x0.x, a[0]); a[1] = fmaf(w0.y, x0.y, a[1]);
        a[2] = fmaf(w0.z, x0.z, a[2]); a[3] = fmaf(w0.w, x0.w, a[3]);
        a[4] = fmaf(w1.x, x1.x, a[4]); a[5] = fmaf(w1.y, x1.y, a[5]);
        a[6] = fmaf(w1.z, x1.z, a[6]); a[7] = fmaf(w1.w, x1.w, a[7]);
    }
    float s = 0.f, ss = 0.f;
#pragma unroll
    for (int i = 0; i < 8; ++i) { s += a[i]; ss = fmaf(a[i], a[i], ss); }
#pragma unroll
    for (int off = 32; off > 0; off >>= 1) {
        s  += __shfl_xor(s, off);
        ss += __shfl_xor(ss, off);
    }
    float mean = s * (1.0f / 512.0f);
    float var  = ss * (1.0f / 512.0f) - mean * mean;
    float rs = rsqrtf(var + 1e-5f);
    float4 w0 = *(const float4*)(nw + d0), w1 = *(const float4*)(nw + d0 + 4);
    float4 b0 = *(const float4*)(nb + d0), b1 = *(const float4*)(nb + d0 + 4);
    f16x8 h;
    h[0] = (f16)((a[0] - mean) * rs * w0.x + b0.x);
    h[1] = (f16)((a[1] - mean) * rs * w0.y + b0.y);
    h[2] = (f16)((a[2] - mean) * rs * w0.z + b0.z);
    h[3] = (f16)((a[3] - mean) * rs * w0.w + b0.w);
    h[4] = (f16)((a[4] - mean) * rs * w1.x + b1.x);
    h[5] = (f16)((a[5] - mean) * rs * w1.y + b1.y);
    h[6] = (f16)((a[6] - mean) * rs * w1.z + b1.z);
    h[7] = (f16)((a[7] - mean) * rs * w1.w + b1.w);
    *(f16x8*)(out + ((size_t)bt << 9) + d0) = h;
}

// ---------------- fp16 MFMA GEMM v3: 128x128 tile, BK=64, 32x32x16, swizzled LDS ----------------
// C(M x N) = A(M x K) . W(N x K)^T ; 256 threads = 4 waves (2x2), wave-tile 64x64.
// LDS: double-buffered [2][A/B][128*64] f16 = 64 KB -> 2 blocks/CU.
// Swizzle: 8 x 16B slots per 128B row; LDS slot sl of row r holds global chunk sl^(r&7)
// (pre-swizzled global source + linear global_load_lds dest; read side applies same XOR).
// One __syncthreads per K-tile (implicit vmcnt(0) drain covers next-tile staging).
// EPI: 0 = fp32 +bias ; 1 = fp16 gelu(+bias) ; 2 = fp32 C += gamma*(v+bias) ; 3 = fp16 *bias

__device__ __forceinline__ void stage128(const f16* __restrict__ g, f16* s,
                                         int K, int kof, int tid) {
    int rr = tid >> 3;
    int sl = tid & 7;
    int gs = sl ^ (rr & 7);
#pragma unroll
    for (int i = 0; i < 4; ++i) {
        int row = rr + (i << 5);
        gload16(g + (size_t)row * K + kof + (gs << 3), s + (row << 6) + (sl << 3));
    }
}

#define MF32(d, a, b) d = __builtin_amdgcn_mfma_f32_32x32x16_f16(a, b, d, 0, 0, 0)

template <int EPI>
__global__ __launch_bounds__(256, 2) void k_hgemm3(const f16* __restrict__ A,
                                                   const f16* __restrict__ W,
                                                   const float* __restrict__ bias,
                                                   const float* __restrict__ gamma,
                                                   void* __restrict__ C,
                                                   int K, int ldc, int nNt) {
    __shared__ f16 lds[2][2][8192];
    int tid = threadIdx.x;
    int nwg = gridDim.x, bid = blockIdx.x;
    int q = nwg >> 3, r = nwg & 7;
    int xcd = bid & 7, lin = bid >> 3;
    int swz = (xcd < r ? xcd * (q + 1) : r * (q + 1) + (xcd - r) * q) + lin;
    int bm = (swz / nNt) << 7;
    int bn = (swz % nNt) << 7;
    const f16* gA = A + (size_t)bm * K;
    const f16* gW = W + (size_t)bn * K;

    int l = tid & 63;
    int wv = tid >> 6;
    int wm = (wv & 1) << 6;    // 2 wave-rows of 64
    int wn = (wv >> 1) << 6;   // 2 wave-cols of 64
    int lr = l & 31;
    int lh = l >> 5;
    int lx = (lr & 7);         // row&7 component for swizzle (tiles 32-aligned)

    f32x16 acc[2][2];
#pragma unroll
    for (int i = 0; i < 2; ++i)
#pragma unroll
        for (int j = 0; j < 2; ++j)
#pragma unroll
            for (int e = 0; e < 16; ++e) acc[i][j][e] = 0.0f;

    int nk = K >> 6;
    stage128(gA, &lds[0][0][0], K, 0, tid);
    stage128(gW, &lds[0][1][0], K, 0, tid);
    __syncthreads();

    for (int t = 0; t < nk; ++t) {
        int cur = t & 1;
        if (t + 1 < nk) {
            stage128(gA, &lds[cur ^ 1][0][0], K, (t + 1) << 6, tid);
            stage128(gW, &lds[cur ^ 1][1][0], K, (t + 1) << 6, tid);
        }
        const f16* sA = &lds[cur][0][0];
        const f16* sB = &lds[cur][1][0];
#pragma unroll
        for (int kq = 0; kq < 4; ++kq) {
            int sx = (((kq << 1) | lh) ^ lx) << 3;
            f16x8 a0 = *(const f16x8*)(sA + ((wm + lr) << 6) + sx);
            f16x8 a1 = *(const f16x8*)(sA + ((wm + 32 + lr) << 6) + sx);
            f16x8 b0 = *(const f16x8*)(sB + ((wn + lr) << 6) + sx);
            f16x8 b1 = *(const f16x8*)(sB + ((wn + 32 + lr) << 6) + sx);
            MF32(acc[0][0], a0, b0); MF32(acc[0][1], a0, b1);
            MF32(acc[1][0], a1, b0); MF32(acc[1][1], a1, b1);
        }
        __syncthreads();
    }

    // epilogue: C/D layout col = lane&31, row = (r&3) + 8*(r>>2) + 4*(lane>>5)
#pragma unroll
    for (int fi = 0; fi < 2; ++fi) {
#pragma unroll
        for (int rg = 0; rg < 16; ++rg) {
            int row = bm + wm + fi * 32 + (rg & 3) + ((rg >> 2) << 3) + (lh << 2);
            size_t moff = (size_t)row * ldc;
#pragma unroll
            for (int fj = 0; fj < 2; ++fj) {
                int col = bn + wn + fj * 32 + lr;
                float v = acc[fi][fj][rg];
                if constexpr (EPI == 0) {
                    ((float*)C)[moff + col] = v + bias[col];
                } else if constexpr (EPI == 1) {
                    ((f16*)C)[moff + col] = (f16)gelu_f(v + bias[col]);
                } else if constexpr (EPI == 2) {
                    ((float*)C)[moff + col] += gamma[col] * (v + bias[col]);
                } else {
                    ((f16*)C)[moff + col] = (f16)(v * bias[col]);
                }
            }
        }
    }
}

// ---------------- head fp32 (stride 1152) -> S fp16 (stride 1088, padded) ----------------
__global__ __launch_bounds__(256) void k_srsi(const float* __restrict__ o,
                                              f16* __restrict__ S) {
    int idx = blockIdx.x * 256 + threadIdx.x;
    if (idx >= BT_ * KI_) return;
    int m = idx / KI_;
    int f2 = idx - m * KI_;
    size_t base = (size_t)m * NPAD_;
    float v = 0.0f;
    if (f2 < NF_) {
        float mag = fminf(expf(o[base + f2]), 100.0f);
        float sn, cs;
        sincosf(o[base + NF_ + f2], &sn, &cs);
        v = mag * cs;
    } else if (f2 < NO2_) {
        int f = f2 - NF_;
        float mag = fminf(expf(o[base + f]), 100.0f);
        float sn, cs;
        sincosf(o[base + NF_ + f], &sn, &cs);
        v = mag * sn;
    }
    S[idx] = (f16)v;
}

// ---------------- overlap-add + win_env + crop (deterministic gather, f16 frames) ------
__global__ __launch_bounds__(256) void k_gather(const f16* __restrict__ frames,
                                                const float* __restrict__ win,
                                                float* __restrict__ out) {
    int idx = blockIdx.x * 256 + threadIdx.x;
    int b  = idx / LOUT_;
    int lp = idx - b * LOUT_;
    int l = lp + (NFFT_ / 2);
    int thi = l >> 8;
    if (thi > T_ - 1) thi = T_ - 1;
    int tlo = l - (NFFT_ - 1) + (HOP_ - 1);
    tlo = (tlo < 0) ? 0 : (tlo >> 8);
    float num = 0.0f, den = 0.0f;
    for (int t = tlo; t <= thi; ++t) {
        int n = l - (t << 8);
        float wv = win[n];
        num += (float)frames[((size_t)(b * T_ + t) << 10) + n];
        den = fmaf(wv, wv, den);
    }
    out[idx] = num / (den + 1e-11f);
}

// ---------------- launch ----------------
extern "C" void kernel_launch(void* const* d_in, const int* in_sizes, int n_in,
                              void* d_out, int out_size, void* d_ws, size_t ws_size,
                              hipStream_t stream) {
    (void)in_sizes; (void)n_in; (void)out_size; (void)ws_size;
    const float* mel     = (const float*)d_in[0];
    const float* embed_w = (const float*)d_in[1];
    const float* embed_b = (const float*)d_in[2];
    const float* norm_w  = (const float*)d_in[3];
    const float* norm_b  = (const float*)d_in[4];
    const float* bdw = (const float*)d_in[5];
    const float* bdb = (const float*)d_in[6];
    const float* bnw = (const float*)d_in[7];
    const float* bnb = (const float*)d_in[8];
    const float* bw1 = (const float*)d_in[9];
    const float* bb1 = (const float*)d_in[10];
    const float* bw2 = (const float*)d_in[11];
    const float* bb2 = (const float*)d_in[12];
    const float* bg  = (const float*)d_in[13];
    const float* fnw = (const float*)d_in[14];
    const float* fnb = (const float*)d_in[15];
    const float* hw  = (const float*)d_in[16];
    const float* hb  = (const float*)d_in[17];
    const float* win = (const float*)d_in[18];

    char* ws = (char*)d_ws;
    // region A: [0, 50.3MB): xbuf fp32 (33.5MB) + ybuf_h fp16 (16.8MB); S_h (35.7MB) overlays later
    float* xbuf   = (float*)ws;
    f16*   ybuf_h = (f16*)(ws + 33554432);
    f16*   S_h    = (f16*)ws;
    // region R: [50.3MB, 134.2MB): hbuf_h fp16 at +33.5MB; A_h / obuf / frames_h at base
    char* R = ws + 50331648;
    f16*   hbuf_h = (f16*)(R + 33554432);
    f16*   A_h    = (f16*)R;
    float* obuf   = (float*)R;
    f16*   frames_h = (f16*)R;
    // region W: [134.2MB, ...): converted weights
    char* Wr = ws + 134217728;
    f16*   w1_h   = (f16*)Wr;                     // 12,582,912
    f16*   w2_h   = (f16*)(Wr + 12582912);        // 12,582,912
    f16*   head_h = (f16*)(Wr + 25165824);        // 1,179,648
    f16*   wmat_h = (f16*)(Wr + 26345472);        // 2,228,224
    f16*   we_h   = (f16*)(Wr + 28573696);        // 1,376,256
    float* hb_pad = (float*)(Wr + 29949952);      // 4,608
    float* dwT    = (float*)(Wr + 29954560);      // 114,688

    const int nW1 = 8 * H_ * D_;
    k_cvt<<<(nW1 + 255) / 256, 256, 0, stream>>>(bw1, w1_h, nW1);
    k_cvt<<<(nW1 + 255) / 256, 256, 0, stream>>>(bw2, w2_h, nW1);
    k_cvt<<<(CM_ * 7 * D_ + 255) / 256, 256, 0, stream>>>(embed_w, we_h, CM_ * 7 * D_);
    k_cvt_head<<<(NPAD_ * D_ + 255) / 256, 256, 0, stream>>>(hw, head_h);
    k_pad_hb<<<5, 256, 0, stream>>>(hb, hb_pad);
    k_cvtdw<<<(8 * 3584 + 255) / 256, 256, 0, stream>>>(bdw, dwT);
    k_build_wmat<<<(NFFT_ * KI_ + 255) / 256, 256, 0, stream>>>(wmat_h);

    // embed conv as im2col + GEMM
    k_im2col<<<(BT_ * KE_ + 255) / 256, 256, 0, stream>>>(mel, A_h);
    k_hgemm3<0><<<128 * 4, 256, 0, stream>>>(A_h, we_h, embed_b, nullptr, xbuf,
                                             KE_, D_, 4);
    k_ln<false><<<BT_, 64, 0, stream>>>(xbuf, xbuf, norm_w, norm_b);

    for (int bl = 0; bl < 8; ++bl) {
        k_dwln<<<BT_, 64, 0, stream>>>(xbuf, dwT + bl * 3584, bdb + bl * D_,
                                       bnw + bl * D_, bnb + bl * D_, ybuf_h);
        k_hgemm3<1><<<128 * 12, 256, 0, stream>>>(ybuf_h, w1_h + (size_t)bl * H_ * D_,
                                                  bb1 + bl * H_, nullptr, hbuf_h,
                                                  D_, H_, 12);
        k_hgemm3<2><<<128 * 4, 256, 0, stream>>>(hbuf_h, w2_h + (size_t)bl * D_ * H_,
                                                 bb2 + bl * D_, bg + bl * D_, xbuf,
                                                 H_, D_, 4);
    }

    k_ln<true><<<BT_, 64, 0, stream>>>(xbuf, ybuf_h, fnw, fnb);
    k_hgemm3<0><<<128 * 9, 256, 0, stream>>>(ybuf_h, head_h, hb_pad, nullptr, obuf,
                                             D_, NPAD_, 9);
    k_srsi<<<(BT_ * KI_ + 255) / 256, 256, 0, stream>>>(obuf, S_h);
    k_hgemm3<3><<<128 * 8, 256, 0, stream>>>(S_h, wmat_h, win, nullptr, frames_h,
                                             KI_, NFFT_, 8);
    k_gather<<<B_ * LOUT_ / 256, 256, 0, stream>>>(frames_h, win, (float*)d_out);
}

// Round 5
// 1302.502 us; speedup vs baseline: 1.0556x; 1.0556x over previous
//
#include <hip/hip_runtime.h>
#include <cmath>

#define B_ 8
#define T_ 2048
#define BT_ 16384
#define D_ 512
#define H_ 1536
#define CM_ 192
#define KE_ 1344      // im2col K = 192*7
#define NFFT_ 1024
#define NF_ 513
#define HOP_ 256
#define NO2_ 1026
#define NPAD_ 1152    // head N padded to tile multiple
#define KI_ 1088      // ISTFT K (= 1026 padded to 64-multiple)
#define LOUT_ 524032

typedef _Float16 f16;
typedef f16 f16x8 __attribute__((ext_vector_type(8)));
typedef float f32x4 __attribute__((ext_vector_type(4)));

__device__ __forceinline__ float gelu_f(float v) {
    return 0.5f * v * (1.0f + erff(v * 0.70710678118654752f));
}

__device__ __forceinline__ void gload16(const void* g, void* s) {
    __builtin_amdgcn_global_load_lds((const __attribute__((address_space(1))) void*)g,
                                     (__attribute__((address_space(3))) void*)s, 16, 0, 0);
}

// ---------------- conversion / prep kernels ----------------

__global__ __launch_bounds__(256) void k_cvt(const float* __restrict__ src,
                                             f16* __restrict__ dst, int n) {
    int i = blockIdx.x * 256 + threadIdx.x;
    if (i < n) dst[i] = (f16)src[i];
}

// head weights (1026,512) -> fp16 (1152,512) zero-padded rows
__global__ __launch_bounds__(256) void k_cvt_head(const float* __restrict__ src,
                                                  f16* __restrict__ dst) {
    int i = blockIdx.x * 256 + threadIdx.x;
    if (i >= NPAD_ * D_) return;
    int row = i >> 9;
    dst[i] = (row < NO2_) ? (f16)src[i] : (f16)0.0f;
}

__global__ __launch_bounds__(256) void k_pad_hb(const float* __restrict__ src,
                                                float* __restrict__ dst) {
    int i = blockIdx.x * 256 + threadIdx.x;
    if (i < NPAD_) dst[i] = (i < NO2_) ? src[i] : 0.0f;
}

// dw (8,512,7) -> dwT[bl][k][d]
__global__ __launch_bounds__(256) void k_cvtdw(const float* __restrict__ dw,
                                               float* __restrict__ dwT) {
    int i = blockIdx.x * 256 + threadIdx.x;
    if (i >= 8 * 7 * 512) return;
    int bl = i / 3584;
    int rem = i - bl * 3584;
    int k = rem >> 9;
    int d = rem & 511;
    dwT[i] = dw[bl * 3584 + d * 7 + k];
}

// ISTFT basis fp16: wmat[n][f2], f2<513: cos*scale ; 513..1025: -sin*scale ; pad 0
__global__ __launch_bounds__(256) void k_build_wmat(f16* __restrict__ wmat) {
    int idx = blockIdx.x * 256 + threadIdx.x;
    if (idx >= NFFT_ * KI_) return;
    int n = idx / KI_;
    int f2 = idx - n * KI_;
    float v = 0.0f;
    if (f2 < NF_) {
        int r = (n * f2) & (NFFT_ - 1);
        float sc = (f2 == 0 || f2 == NF_ - 1) ? (1.0f / NFFT_) : (2.0f / NFFT_);
        v = cospif((float)r * (2.0f / NFFT_)) * sc;
    } else if (f2 < NO2_) {
        int f = f2 - NF_;
        int r = (n * f) & (NFFT_ - 1);
        float sc = (f == 0 || f == NF_ - 1) ? (1.0f / NFFT_) : (2.0f / NFFT_);
        v = -sinpif((float)r * (2.0f / NFFT_)) * sc;
    }
    wmat[idx] = (f16)v;
}

// im2col for embed conv: A[bt][c*7+k] = mel[b][c][t+k-3]
__global__ __launch_bounds__(256) void k_im2col(const float* __restrict__ mel,
                                                f16* __restrict__ A) {
    int idx = blockIdx.x * 256 + threadIdx.x;
    if (idx >= BT_ * KE_) return;
    int bt = idx / KE_;
    int ck = idx - bt * KE_;
    int c = ck / 7;
    int kk = ck - c * 7;
    int b = bt >> 11;
    int t = bt & (T_ - 1);
    int tt = t + kk - 3;
    float v = (tt >= 0 && tt < T_) ? mel[((size_t)b * CM_ + c) * T_ + tt] : 0.0f;
    A[idx] = (f16)v;
}

// ---------------- LayerNorm over D=512, one wave per row ----------------
template <bool HOUT>
__global__ __launch_bounds__(64) void k_ln(const float* __restrict__ in,
                                           void* __restrict__ out,
                                           const float* __restrict__ w,
                                           const float* __restrict__ b) {
    int row = blockIdx.x;
    int lane = threadIdx.x;
    const float* p = in + (size_t)row * D_ + lane * 8;
    float4 v0 = *(const float4*)p;
    float4 v1 = *(const float4*)(p + 4);
    float s  = v0.x + v0.y + v0.z + v0.w + v1.x + v1.y + v1.z + v1.w;
    float ss = v0.x * v0.x + v0.y * v0.y + v0.z * v0.z + v0.w * v0.w +
               v1.x * v1.x + v1.y * v1.y + v1.z * v1.z + v1.w * v1.w;
#pragma unroll
    for (int off = 32; off > 0; off >>= 1) {
        s  += __shfl_xor(s, off);
        ss += __shfl_xor(ss, off);
    }
    float mean = s * (1.0f / 512.0f);
    float var  = ss * (1.0f / 512.0f) - mean * mean;
    float rs = rsqrtf(var + 1e-5f);
    const float* wp = w + lane * 8;
    const float* bp = b + lane * 8;
    float4 w0 = *(const float4*)wp, w1 = *(const float4*)(wp + 4);
    float4 b0 = *(const float4*)bp, b1 = *(const float4*)(bp + 4);
    float o[8];
    o[0] = (v0.x - mean) * rs * w0.x + b0.x;
    o[1] = (v0.y - mean) * rs * w0.y + b0.y;
    o[2] = (v0.z - mean) * rs * w0.z + b0.z;
    o[3] = (v0.w - mean) * rs * w0.w + b0.w;
    o[4] = (v1.x - mean) * rs * w1.x + b1.x;
    o[5] = (v1.y - mean) * rs * w1.y + b1.y;
    o[6] = (v1.z - mean) * rs * w1.z + b1.z;
    o[7] = (v1.w - mean) * rs * w1.w + b1.w;
    if constexpr (HOUT) {
        f16x8 h;
#pragma unroll
        for (int i = 0; i < 8; ++i) h[i] = (f16)o[i];
        *(f16x8*)((f16*)out + (size_t)row * D_ + lane * 8) = h;
    } else {
        float* q = (float*)out + (size_t)row * D_ + lane * 8;
        *(float4*)q = make_float4(o[0], o[1], o[2], o[3]);
        *(float4*)(q + 4) = make_float4(o[4], o[5], o[6], o[7]);
    }
}

// ---------------- fused depthwise conv (k=7 over t) + LayerNorm -> fp16 ----------------
__global__ __launch_bounds__(64) void k_dwln(const float* __restrict__ x,
                                             const float* __restrict__ dwT,
                                             const float* __restrict__ db,
                                             const float* __restrict__ nw,
                                             const float* __restrict__ nb,
                                             f16* __restrict__ out) {
    int bt = blockIdx.x;
    int t = bt & (T_ - 1);
    int base = bt - t;
    int lane = threadIdx.x;
    int d0 = lane << 3;
    float a[8];
    *(float4*)&a[0] = *(const float4*)(db + d0);
    *(float4*)&a[4] = *(const float4*)(db + d0 + 4);
#pragma unroll
    for (int k = 0; k < 7; ++k) {
        int tt = t + k - 3;
        if (tt < 0 || tt >= T_) continue;
        const float* xp = x + (((size_t)(base + tt)) << 9) + d0;
        float4 x0 = *(const float4*)xp, x1 = *(const float4*)(xp + 4);
        const float* wp = dwT + (k << 9) + d0;
        float4 w0 = *(const float4*)wp, w1 = *(const float4*)(wp + 4);
        a[0] = fmaf(w0.x, x0.x, a[0]); a[1] = fmaf(w0.y, x0.y, a[1]);
        a[2] = fmaf(w0.z, x0.z, a[2]); a[3] = fmaf(w0.w, x0.w, a[3]);
        a[4] = fmaf(w1.x, x1.x, a[4]); a[5] = fmaf(w1.y, x1.y, a[5]);
        a[6] = fmaf(w1.z, x1.z, a[6]); a[7] = fmaf(w1.w, x1.w, a[7]);
    }
    float s = 0.f, ss = 0.f;
#pragma unroll
    for (int i = 0; i < 8; ++i) { s += a[i]; ss = fmaf(a[i], a[i], ss); }
#pragma unroll
    for (int off = 32; off > 0; off >>= 1) {
        s  += __shfl_xor(s, off);
        ss += __shfl_xor(ss, off);
    }
    float mean = s * (1.0f / 512.0f);
    float var  = ss * (1.0f / 512.0f) - mean * mean;
    float rs = rsqrtf(var + 1e-5f);
    float4 w0 = *(const float4*)(nw + d0), w1 = *(const float4*)(nw + d0 + 4);
    float4 b0 = *(const float4*)(nb + d0), b1 = *(const float4*)(nb + d0 + 4);
    f16x8 h;
    h[0] = (f16)((a[0] - mean) * rs * w0.x + b0.x);
    h[1] = (f16)((a[1] - mean) * rs * w0.y + b0.y);
    h[2] = (f16)((a[2] - mean) * rs * w0.z + b0.z);
    h[3] = (f16)((a[3] - mean) * rs * w0.w + b0.w);
    h[4] = (f16)((a[4] - mean) * rs * w1.x + b1.x);
    h[5] = (f16)((a[5] - mean) * rs * w1.y + b1.y);
    h[6] = (f16)((a[6] - mean) * rs * w1.z + b1.z);
    h[7] = (f16)((a[7] - mean) * rs * w1.w + b1.w);
    *(f16x8*)(out + ((size_t)bt << 9) + d0) = h;
}

// ---------------- fp16 MFMA GEMM v4: 128x128 tile, BK=64, 16x16x32, zero-conflict LDS --
// C(M x N) = A(M x K) . W(N x K)^T ; 256 threads = 4 waves (2x2), wave-tile 64x64 (4x4 frags).
// LDS: double-buffered [2][A/B][128 rows x 64 f16] = 64 KB -> 2 blocks/CU.
// Swizzle (both-sides, rule #21): LDS slot sl of row r holds global 16B-chunk sl^(r&7)
// (pre-swizzled global source + linear global_load_lds dest); read slot = chunk^(row&7).
// Read geometry = round-3-verified ZERO-conflict pattern: rows wm+i*16+lr (lr=lane&15),
// slot lk^(lr&7) / (lk+4)^(lr&7) (lk=lane>>4), 128 B rows.
// One __syncthreads per K-tile (its vmcnt(0) drain covers next-tile staging).
// EPI: 0 = fp32 +bias ; 1 = fp16 gelu(+bias) ; 2 = fp32 C += gamma*(v+bias) ; 3 = fp16 *bias

__device__ __forceinline__ void stage128(const f16* __restrict__ g, f16* s,
                                         int K, int kof, int tid) {
    int rr = tid >> 3;
    int sl = tid & 7;
    int gs = sl ^ (rr & 7);
#pragma unroll
    for (int i = 0; i < 4; ++i) {
        int row = rr + (i << 5);
        gload16(g + (size_t)row * K + kof + (gs << 3), s + (row << 6) + (sl << 3));
    }
}

#define MF(d, a, b) d = __builtin_amdgcn_mfma_f32_16x16x32_f16(a, b, d, 0, 0, 0)

template <int EPI>
__global__ __launch_bounds__(256, 2) void k_hgemm4(const f16* __restrict__ A,
                                                   const f16* __restrict__ W,
                                                   const float* __restrict__ bias,
                                                   const float* __restrict__ gamma,
                                                   void* __restrict__ C,
                                                   int K, int ldc, int nNt) {
    __shared__ f16 lds[2][2][8192];
    int tid = threadIdx.x;
    int nwg = gridDim.x, bid = blockIdx.x;
    int q = nwg >> 3, r = nwg & 7;
    int xcd = bid & 7, lin = bid >> 3;
    int swz = (xcd < r ? xcd * (q + 1) : r * (q + 1) + (xcd - r) * q) + lin;
    int bm = (swz / nNt) << 7;
    int bn = (swz % nNt) << 7;
    const f16* gA = A + (size_t)bm * K;
    const f16* gW = W + (size_t)bn * K;

    int l = tid & 63;
    int wv = tid >> 6;
    int wm = (wv & 1) << 6;    // 2 wave-rows of 64
    int wn = (wv >> 1) << 6;   // 2 wave-cols of 64
    int lr = l & 15;
    int lk = l >> 4;
    int sx0 = ((lk ^ (lr & 7)) << 3);          // k-chunk 0..3 (k 0..31), swizzled
    int sx1 = (((lk + 4) ^ (lr & 7)) << 3);    // k-chunk 4..7 (k 32..63)

    f32x4 acc[4][4];
#pragma unroll
    for (int i = 0; i < 4; ++i)
#pragma unroll
        for (int j = 0; j < 4; ++j) acc[i][j] = {0.f, 0.f, 0.f, 0.f};

    int nk = K >> 6;
    stage128(gA, &lds[0][0][0], K, 0, tid);
    stage128(gW, &lds[0][1][0], K, 0, tid);
    __syncthreads();

    for (int t = 0; t < nk; ++t) {
        int cur = t & 1;
        if (t + 1 < nk) {
            stage128(gA, &lds[cur ^ 1][0][0], K, (t + 1) << 6, tid);
            stage128(gW, &lds[cur ^ 1][1][0], K, (t + 1) << 6, tid);
        }
        const f16* sA = &lds[cur][0][0];
        const f16* sB = &lds[cur][1][0];
        f16x8 af[4], bf[4];
        // ---- k-half 0 (k 0..31)
#pragma unroll
        for (int i = 0; i < 4; ++i)
            af[i] = *(const f16x8*)(sA + ((wm + i * 16 + lr) << 6) + sx0);
#pragma unroll
        for (int j = 0; j < 4; ++j)
            bf[j] = *(const f16x8*)(sB + ((wn + j * 16 + lr) << 6) + sx0);
#pragma unroll
        for (int i = 0; i < 4; ++i)
#pragma unroll
            for (int j = 0; j < 4; ++j) MF(acc[i][j], af[i], bf[j]);
        // ---- k-half 1 (k 32..63)
#pragma unroll
        for (int i = 0; i < 4; ++i)
            af[i] = *(const f16x8*)(sA + ((wm + i * 16 + lr) << 6) + sx1);
#pragma unroll
        for (int j = 0; j < 4; ++j)
            bf[j] = *(const f16x8*)(sB + ((wn + j * 16 + lr) << 6) + sx1);
#pragma unroll
        for (int i = 0; i < 4; ++i)
#pragma unroll
            for (int j = 0; j < 4; ++j) MF(acc[i][j], af[i], bf[j]);
        __syncthreads();
    }

    // epilogue: C/D layout col = lane&15, row = (lane>>4)*4 + reg (m89-verified)
    int lk4 = lk << 2;
#pragma unroll
    for (int i = 0; i < 4; ++i) {
#pragma unroll
        for (int rr = 0; rr < 4; ++rr) {
            int row = bm + wm + i * 16 + lk4 + rr;
            size_t moff = (size_t)row * ldc;
#pragma unroll
            for (int j = 0; j < 4; ++j) {
                int col = bn + wn + j * 16 + lr;
                float v = acc[i][j][rr];
                if constexpr (EPI == 0) {
                    ((float*)C)[moff + col] = v + bias[col];
                } else if constexpr (EPI == 1) {
                    ((f16*)C)[moff + col] = (f16)gelu_f(v + bias[col]);
                } else if constexpr (EPI == 2) {
                    ((float*)C)[moff + col] += gamma[col] * (v + bias[col]);
                } else {
                    ((f16*)C)[moff + col] = (f16)(v * bias[col]);
                }
            }
        }
    }
}

// ---------------- head fp32 (stride 1152) -> S fp16 (stride 1088, padded) ----------------
__global__ __launch_bounds__(256) void k_srsi(const float* __restrict__ o,
                                              f16* __restrict__ S) {
    int idx = blockIdx.x * 256 + threadIdx.x;
    if (idx >= BT_ * KI_) return;
    int m = idx / KI_;
    int f2 = idx - m * KI_;
    size_t base = (size_t)m * NPAD_;
    float v = 0.0f;
    if (f2 < NF_) {
        float mag = fminf(expf(o[base + f2]), 100.0f);
        float sn, cs;
        sincosf(o[base + NF_ + f2], &sn, &cs);
        v = mag * cs;
    } else if (f2 < NO2_) {
        int f = f2 - NF_;
        float mag = fminf(expf(o[base + f]), 100.0f);
        float sn, cs;
        sincosf(o[base + NF_ + f], &sn, &cs);
        v = mag * sn;
    }
    S[idx] = (f16)v;
}

// ---------------- overlap-add + win_env + crop (deterministic gather, f16 frames) ------
__global__ __launch_bounds__(256) void k_gather(const f16* __restrict__ frames,
                                                const float* __restrict__ win,
                                                float* __restrict__ out) {
    int idx = blockIdx.x * 256 + threadIdx.x;
    int b  = idx / LOUT_;
    int lp = idx - b * LOUT_;
    int l = lp + (NFFT_ / 2);
    int thi = l >> 8;
    if (thi > T_ - 1) thi = T_ - 1;
    int tlo = l - (NFFT_ - 1) + (HOP_ - 1);
    tlo = (tlo < 0) ? 0 : (tlo >> 8);
    float num = 0.0f, den = 0.0f;
    for (int t = tlo; t <= thi; ++t) {
        int n = l - (t << 8);
        float wv = win[n];
        num += (float)frames[((size_t)(b * T_ + t) << 10) + n];
        den = fmaf(wv, wv, den);
    }
    out[idx] = num / (den + 1e-11f);
}

// ---------------- launch ----------------
extern "C" void kernel_launch(void* const* d_in, const int* in_sizes, int n_in,
                              void* d_out, int out_size, void* d_ws, size_t ws_size,
                              hipStream_t stream) {
    (void)in_sizes; (void)n_in; (void)out_size; (void)ws_size;
    const float* mel     = (const float*)d_in[0];
    const float* embed_w = (const float*)d_in[1];
    const float* embed_b = (const float*)d_in[2];
    const float* norm_w  = (const float*)d_in[3];
    const float* norm_b  = (const float*)d_in[4];
    const float* bdw = (const float*)d_in[5];
    const float* bdb = (const float*)d_in[6];
    const float* bnw = (const float*)d_in[7];
    const float* bnb = (const float*)d_in[8];
    const float* bw1 = (const float*)d_in[9];
    const float* bb1 = (const float*)d_in[10];
    const float* bw2 = (const float*)d_in[11];
    const float* bb2 = (const float*)d_in[12];
    const float* bg  = (const float*)d_in[13];
    const float* fnw = (const float*)d_in[14];
    const float* fnb = (const float*)d_in[15];
    const float* hw  = (const float*)d_in[16];
    const float* hb  = (const float*)d_in[17];
    const float* win = (const float*)d_in[18];

    char* ws = (char*)d_ws;
    // region A: [0, 50.3MB): xbuf fp32 (33.5MB) + ybuf_h fp16 (16.8MB); S_h (35.7MB) overlays later
    float* xbuf   = (float*)ws;
    f16*   ybuf_h = (f16*)(ws + 33554432);
    f16*   S_h    = (f16*)ws;
    // region R: [50.3MB, 134.2MB): hbuf_h fp16 at +33.5MB; A_h / obuf / frames_h at base
    char* R = ws + 50331648;
    f16*   hbuf_h = (f16*)(R + 33554432);
    f16*   A_h    = (f16*)R;
    float* obuf   = (float*)R;
    f16*   frames_h = (f16*)R;
    // region W: [134.2MB, ...): converted weights
    char* Wr = ws + 134217728;
    f16*   w1_h   = (f16*)Wr;                     // 12,582,912
    f16*   w2_h   = (f16*)(Wr + 12582912);        // 12,582,912
    f16*   head_h = (f16*)(Wr + 25165824);        // 1,179,648
    f16*   wmat_h = (f16*)(Wr + 26345472);        // 2,228,224
    f16*   we_h   = (f16*)(Wr + 28573696);        // 1,376,256
    float* hb_pad = (float*)(Wr + 29949952);      // 4,608
    float* dwT    = (float*)(Wr + 29954560);      // 114,688

    const int nW1 = 8 * H_ * D_;
    k_cvt<<<(nW1 + 255) / 256, 256, 0, stream>>>(bw1, w1_h, nW1);
    k_cvt<<<(nW1 + 255) / 256, 256, 0, stream>>>(bw2, w2_h, nW1);
    k_cvt<<<(CM_ * 7 * D_ + 255) / 256, 256, 0, stream>>>(embed_w, we_h, CM_ * 7 * D_);
    k_cvt_head<<<(NPAD_ * D_ + 255) / 256, 256, 0, stream>>>(hw, head_h);
    k_pad_hb<<<5, 256, 0, stream>>>(hb, hb_pad);
    k_cvtdw<<<(8 * 3584 + 255) / 256, 256, 0, stream>>>(bdw, dwT);
    k_build_wmat<<<(NFFT_ * KI_ + 255) / 256, 256, 0, stream>>>(wmat_h);

    // embed conv as im2col + GEMM
    k_im2col<<<(BT_ * KE_ + 255) / 256, 256, 0, stream>>>(mel, A_h);
    k_hgemm4<0><<<128 * 4, 256, 0, stream>>>(A_h, we_h, embed_b, nullptr, xbuf,
                                             KE_, D_, 4);
    k_ln<false><<<BT_, 64, 0, stream>>>(xbuf, xbuf, norm_w, norm_b);

    for (int bl = 0; bl < 8; ++bl) {
        k_dwln<<<BT_, 64, 0, stream>>>(xbuf, dwT + bl * 3584, bdb + bl * D_,
                                       bnw + bl * D_, bnb + bl * D_, ybuf_h);
        k_hgemm4<1><<<128 * 12, 256, 0, stream>>>(ybuf_h, w1_h + (size_t)bl * H_ * D_,
                                                  bb1 + bl * H_, nullptr, hbuf_h,
                                                  D_, H_, 12);
        k_hgemm4<2><<<128 * 4, 256, 0, stream>>>(hbuf_h, w2_h + (size_t)bl * D_ * H_,
                                                 bb2 + bl * D_, bg + bl * D_, xbuf,
                                                 H_, D_, 4);
    }

    k_ln<true><<<BT_, 64, 0, stream>>>(xbuf, ybuf_h, fnw, fnb);
    k_hgemm4<0><<<128 * 9, 256, 0, stream>>>(ybuf_h, head_h, hb_pad, nullptr, obuf,
                                             D_, NPAD_, 9);
    k_srsi<<<(BT_ * KI_ + 255) / 256, 256, 0, stream>>>(obuf, S_h);
    k_hgemm4<3><<<128 * 8, 256, 0, stream>>>(S_h, wmat_h, win, nullptr, frames_h,
                                             KI_, NFFT_, 8);
    k_gather<<<B_ * LOUT_ / 256, 256, 0, stream>>>(frames_h, win, (float*)d_out);
}

// Round 6
// 1224.576 us; speedup vs baseline: 1.1228x; 1.0636x over previous
//
#include <hip/hip_runtime.h>
#include <cmath>

#define B_ 8
#define T_ 2048
#define BT_ 16384
#define D_ 512
#define H_ 1536
#define CM_ 192
#define KE_ 1344      // im2col K = 192*7 (divisible by 32)
#define NFFT_ 1024
#define NF_ 513
#define HOP_ 256
#define NO2_ 1026
#define NPAD_ 1152    // head N padded to tile multiple
#define KI_ 1088      // ISTFT K (= 1026 padded to 32/64-multiple)
#define LOUT_ 524032

typedef _Float16 f16;
typedef f16 f16x8 __attribute__((ext_vector_type(8)));
typedef float f32x4 __attribute__((ext_vector_type(4)));

// tanh-form GELU: |err| vs exact-erf gelu <= ~3e-4, far under budget
__device__ __forceinline__ float gelu_f(float v) {
    float u = 0.7978845608028654f * v * (1.0f + 0.044715f * v * v);
    float e = __expf(2.0f * u);
    float t = 1.0f - 2.0f * __builtin_amdgcn_rcpf(e + 1.0f);
    return 0.5f * v * (1.0f + t);
}

__device__ __forceinline__ void gload16(const void* g, void* s) {
    __builtin_amdgcn_global_load_lds((const __attribute__((address_space(1))) void*)g,
                                     (__attribute__((address_space(3))) void*)s, 16, 0, 0);
}

// ---------------- conversion / prep kernels ----------------

__global__ __launch_bounds__(256) void k_cvt(const float* __restrict__ src,
                                             f16* __restrict__ dst, int n) {
    int i = blockIdx.x * 256 + threadIdx.x;
    if (i < n) dst[i] = (f16)src[i];
}

// head weights (1026,512) -> fp16 (1152,512) zero-padded rows
__global__ __launch_bounds__(256) void k_cvt_head(const float* __restrict__ src,
                                                  f16* __restrict__ dst) {
    int i = blockIdx.x * 256 + threadIdx.x;
    if (i >= NPAD_ * D_) return;
    int row = i >> 9;
    dst[i] = (row < NO2_) ? (f16)src[i] : (f16)0.0f;
}

__global__ __launch_bounds__(256) void k_pad_hb(const float* __restrict__ src,
                                                float* __restrict__ dst) {
    int i = blockIdx.x * 256 + threadIdx.x;
    if (i < NPAD_) dst[i] = (i < NO2_) ? src[i] : 0.0f;
}

// dw (8,512,7) -> dwT[bl][k][d]
__global__ __launch_bounds__(256) void k_cvtdw(const float* __restrict__ dw,
                                               float* __restrict__ dwT) {
    int i = blockIdx.x * 256 + threadIdx.x;
    if (i >= 8 * 7 * 512) return;
    int bl = i / 3584;
    int rem = i - bl * 3584;
    int k = rem >> 9;
    int d = rem & 511;
    dwT[i] = dw[bl * 3584 + d * 7 + k];
}

// ISTFT basis fp16: wmat[n][f2], f2<513: cos*scale ; 513..1025: -sin*scale ; pad 0
__global__ __launch_bounds__(256) void k_build_wmat(f16* __restrict__ wmat) {
    int idx = blockIdx.x * 256 + threadIdx.x;
    if (idx >= NFFT_ * KI_) return;
    int n = idx / KI_;
    int f2 = idx - n * KI_;
    float v = 0.0f;
    if (f2 < NF_) {
        int r = (n * f2) & (NFFT_ - 1);
        float sc = (f2 == 0 || f2 == NF_ - 1) ? (1.0f / NFFT_) : (2.0f / NFFT_);
        v = cospif((float)r * (2.0f / NFFT_)) * sc;
    } else if (f2 < NO2_) {
        int f = f2 - NF_;
        int r = (n * f) & (NFFT_ - 1);
        float sc = (f == 0 || f == NF_ - 1) ? (1.0f / NFFT_) : (2.0f / NFFT_);
        v = -sinpif((float)r * (2.0f / NFFT_)) * sc;
    }
    wmat[idx] = (f16)v;
}

// im2col for embed conv, 8 elems/thread: A[bt][c*7+k] = mel[b][c][t+k-3]
__global__ __launch_bounds__(256) void k_im2col(const float* __restrict__ mel,
                                                f16* __restrict__ A) {
    int idx = blockIdx.x * 256 + threadIdx.x;
    if (idx >= BT_ * KE_ / 8) return;
    int base = idx << 3;
    int bt = base / KE_;
    int ck = base - bt * KE_;
    int c = ck / 7;
    int kk = ck - c * 7;
    int b = bt >> 11;
    int t = bt & (T_ - 1);
    const float* mp = mel + ((size_t)b * CM_ + c) * T_;
    f16x8 v;
#pragma unroll
    for (int i = 0; i < 8; ++i) {
        int tt = t + kk - 3;
        v[i] = (tt >= 0 && tt < T_) ? (f16)mp[tt] : (f16)0.0f;
        if (++kk == 7) { kk = 0; mp += T_; }
    }
    *(f16x8*)(A + base) = v;
}

// ---------------- LayerNorm over D=512, one wave per row ----------------
template <bool HOUT>
__global__ __launch_bounds__(64) void k_ln(const float* __restrict__ in,
                                           void* __restrict__ out,
                                           const float* __restrict__ w,
                                           const float* __restrict__ b) {
    int row = blockIdx.x;
    int lane = threadIdx.x;
    const float* p = in + (size_t)row * D_ + lane * 8;
    float4 v0 = *(const float4*)p;
    float4 v1 = *(const float4*)(p + 4);
    float s  = v0.x + v0.y + v0.z + v0.w + v1.x + v1.y + v1.z + v1.w;
    float ss = v0.x * v0.x + v0.y * v0.y + v0.z * v0.z + v0.w * v0.w +
               v1.x * v1.x + v1.y * v1.y + v1.z * v1.z + v1.w * v1.w;
#pragma unroll
    for (int off = 32; off > 0; off >>= 1) {
        s  += __shfl_xor(s, off);
        ss += __shfl_xor(ss, off);
    }
    float mean = s * (1.0f / 512.0f);
    float var  = ss * (1.0f / 512.0f) - mean * mean;
    float rs = rsqrtf(var + 1e-5f);
    const float* wp = w + lane * 8;
    const float* bp = b + lane * 8;
    float4 w0 = *(const float4*)wp, w1 = *(const float4*)(wp + 4);
    float4 b0 = *(const float4*)bp, b1 = *(const float4*)(bp + 4);
    float o[8];
    o[0] = (v0.x - mean) * rs * w0.x + b0.x;
    o[1] = (v0.y - mean) * rs * w0.y + b0.y;
    o[2] = (v0.z - mean) * rs * w0.z + b0.z;
    o[3] = (v0.w - mean) * rs * w0.w + b0.w;
    o[4] = (v1.x - mean) * rs * w1.x + b1.x;
    o[5] = (v1.y - mean) * rs * w1.y + b1.y;
    o[6] = (v1.z - mean) * rs * w1.z + b1.z;
    o[7] = (v1.w - mean) * rs * w1.w + b1.w;
    if constexpr (HOUT) {
        f16x8 h;
#pragma unroll
        for (int i = 0; i < 8; ++i) h[i] = (f16)o[i];
        *(f16x8*)((f16*)out + (size_t)row * D_ + lane * 8) = h;
    } else {
        float* q = (float*)out + (size_t)row * D_ + lane * 8;
        *(float4*)q = make_float4(o[0], o[1], o[2], o[3]);
        *(float4*)(q + 4) = make_float4(o[4], o[5], o[6], o[7]);
    }
}

// ---------------- fused depthwise conv (k=7 over t) + LayerNorm -> fp16 ----------------
__global__ __launch_bounds__(64) void k_dwln(const float* __restrict__ x,
                                             const float* __restrict__ dwT,
                                             const float* __restrict__ db,
                                             const float* __restrict__ nw,
                                             const float* __restrict__ nb,
                                             f16* __restrict__ out) {
    int bt = blockIdx.x;
    int t = bt & (T_ - 1);
    int base = bt - t;
    int lane = threadIdx.x;
    int d0 = lane << 3;
    float a[8];
    *(float4*)&a[0] = *(const float4*)(db + d0);
    *(float4*)&a[4] = *(const float4*)(db + d0 + 4);
#pragma unroll
    for (int k = 0; k < 7; ++k) {
        int tt = t + k - 3;
        if (tt < 0 || tt >= T_) continue;
        const float* xp = x + (((size_t)(base + tt)) << 9) + d0;
        float4 x0 = *(const float4*)xp, x1 = *(const float4*)(xp + 4);
        const float* wp = dwT + (k << 9) + d0;
        float4 w0 = *(const float4*)wp, w1 = *(const float4*)(wp + 4);
        a[0] = fmaf(w0.x, x0.x, a[0]); a[1] = fmaf(w0.y, x0.y, a[1]);
        a[2] = fmaf(w0.z, x0.z, a[2]); a[3] = fmaf(w0.w, x0.w, a[3]);
        a[4] = fmaf(w1.x, x1.x, a[4]); a[5] = fmaf(w1.y, x1.y, a[5]);
        a[6] = fmaf(w1.z, x1.z, a[6]); a[7] = fmaf(w1.w, x1.w, a[7]);
    }
    float s = 0.f, ss = 0.f;
#pragma unroll
    for (int i = 0; i < 8; ++i) { s += a[i]; ss = fmaf(a[i], a[i], ss); }
#pragma unroll
    for (int off = 32; off > 0; off >>= 1) {
        s  += __shfl_xor(s, off);
        ss += __shfl_xor(ss, off);
    }
    float mean = s * (1.0f / 512.0f);
    float var  = ss * (1.0f / 512.0f) - mean * mean;
    float rs = rsqrtf(var + 1e-5f);
    float4 w0 = *(const float4*)(nw + d0), w1 = *(const float4*)(nw + d0 + 4);
    float4 b0 = *(const float4*)(nb + d0), b1 = *(const float4*)(nb + d0 + 4);
    f16x8 h;
    h[0] = (f16)((a[0] - mean) * rs * w0.x + b0.x);
    h[1] = (f16)((a[1] - mean) * rs * w0.y + b0.y);
    h[2] = (f16)((a[2] - mean) * rs * w0.z + b0.z);
    h[3] = (f16)((a[3] - mean) * rs * w0.w + b0.w);
    h[4] = (f16)((a[4] - mean) * rs * w1.x + b1.x);
    h[5] = (f16)((a[5] - mean) * rs * w1.y + b1.y);
    h[6] = (f16)((a[6] - mean) * rs * w1.z + b1.z);
    h[7] = (f16)((a[7] - mean) * rs * w1.w + b1.w);
    *(f16x8*)(out + ((size_t)bt << 9) + d0) = h;
}

// ---- fp16 MFMA GEMM v5: 128x128 tile, BK=32, 16x16x32, 3-ring LDS + counted vmcnt ----
// C(M x N) = A(M x K) . W(N x K)^T ; 256 threads = 4 waves (2x2), wave-tile 64x64 (4x4).
// LDS: 3-deep ring of {A 128x32, B 128x32} f16 tiles = 48 KB -> 3 blocks/CU.
// Tile packing: 64 double-rows x 128 B; slot(0..7) = ((row&1)<<2)|chunk, stored at
// slot^(dr&7) via pre-swizzled GLOBAL source + linear global_load_lds dest (rule #21);
// reads apply the same XOR -> same 128 B bank geometry that measured 0 conflicts (r5).
// Pipeline (T3/T4 min recipe): issue stage(t+2) -> ds_read(t) -> MFMA -> vmcnt(4)
// (t+1 landed, t+2 still in flight) -> s_barrier. Never vmcnt(0) in-loop.
// EPI: 0 = fp32 +bias ; 1 = fp16 gelu(+bias) ; 2 = fp32 C += gamma*(v+bias) ; 3 = fp16 *bias

#define TSZ_ 4096   // f16 elems per matrix tile (128x32)

__device__ __forceinline__ void stage32(const f16* __restrict__ g, f16* s,
                                        int K, int kof, int tid) {
    int dr0 = tid >> 3;        // 0..31
    int sl  = tid & 7;
#pragma unroll
    for (int i = 0; i < 2; ++i) {
        int d  = dr0 + (i << 5);           // double-row 0..63
        int gs = sl ^ (d & 7);             // pre-swizzled global slot
        int row = (d << 1) + (gs >> 2);
        int kc  = gs & 3;
        gload16(g + (size_t)row * K + kof + (kc << 3),
                s + (d << 6) + (sl << 3)); // linear dest: wave base + lane*16B
    }
}

#define MF(d, a, b) d = __builtin_amdgcn_mfma_f32_16x16x32_f16(a, b, d, 0, 0, 0)

template <int EPI>
__global__ __launch_bounds__(256, 3) void k_hgemm5(const f16* __restrict__ A,
                                                   const f16* __restrict__ W,
                                                   const float* __restrict__ bias,
                                                   const float* __restrict__ gamma,
                                                   void* __restrict__ C,
                                                   int K, int ldc, int nNt) {
    __shared__ f16 lds[3 * 2 * TSZ_];
    int tid = threadIdx.x;
    int nwg = gridDim.x, bid = blockIdx.x;
    int q = nwg >> 3, r = nwg & 7;
    int xcd = bid & 7, lin = bid >> 3;
    int swz = (xcd < r ? xcd * (q + 1) : r * (q + 1) + (xcd - r) * q) + lin;
    int bm = (swz / nNt) << 7;
    int bn = (swz % nNt) << 7;
    const f16* gA = A + (size_t)bm * K;
    const f16* gW = W + (size_t)bn * K;

    int l = tid & 63;
    int wv = tid >> 6;
    int wm = (wv & 1) << 6;    // 2 wave-rows of 64
    int wn = (wv >> 1) << 6;   // 2 wave-cols of 64
    int lr = l & 15;
    int lk = l >> 4;
    int lrh = lr >> 1;
    int s0l = ((lr & 1) << 2) | lk;   // logical slot for this lane's (row-half, chunk)

    // loop-invariant read offsets (f16 units)
    int offA[4], offB[4];
#pragma unroll
    for (int i = 0; i < 4; ++i) {
        int dA = (wm >> 1) + i * 8 + lrh;
        offA[i] = (dA << 6) + ((s0l ^ (dA & 7)) << 3);
        int dB = (wn >> 1) + i * 8 + lrh;
        offB[i] = (dB << 6) + ((s0l ^ (dB & 7)) << 3);
    }

    f32x4 acc[4][4];
#pragma unroll
    for (int i = 0; i < 4; ++i)
#pragma unroll
        for (int j = 0; j < 4; ++j) acc[i][j] = {0.f, 0.f, 0.f, 0.f};

    int nk = K >> 5;
    f16* s0 = lds;
    f16* s1 = lds + 2 * TSZ_;
    f16* s2 = lds + 4 * TSZ_;

    // prologue: stage tiles 0,1 (8 loads); wait for tile 0 (4 outstanding allowed)
    stage32(gA, s0, K, 0, tid);        stage32(gW, s0 + TSZ_, K, 0, tid);
    stage32(gA, s1, K, 32, tid);       stage32(gW, s1 + TSZ_, K, 32, tid);
    asm volatile("s_waitcnt vmcnt(4)" ::: "memory");
    __builtin_amdgcn_s_barrier();

    for (int t = 0; t < nk; ++t) {
        bool stg = (t + 2 < nk);
        if (stg) {
            int ko = (t + 2) << 5;
            stage32(gA, s2, K, ko, tid);
            stage32(gW, s2 + TSZ_, K, ko, tid);
        }
        f16x8 af[4], bf[4];
#pragma unroll
        for (int i = 0; i < 4; ++i) af[i] = *(const f16x8*)(s0 + offA[i]);
#pragma unroll
        for (int j = 0; j < 4; ++j) bf[j] = *(const f16x8*)(s0 + TSZ_ + offB[j]);
        __builtin_amdgcn_s_setprio(1);
#pragma unroll
        for (int i = 0; i < 4; ++i)
#pragma unroll
            for (int j = 0; j < 4; ++j) MF(acc[i][j], af[i], bf[j]);
        __builtin_amdgcn_s_setprio(0);
        if (stg)               asm volatile("s_waitcnt vmcnt(4)" ::: "memory");
        else if (t + 1 < nk)   asm volatile("s_waitcnt vmcnt(0)" ::: "memory");
        if (t + 1 < nk) {
            __builtin_amdgcn_s_barrier();
            asm volatile("" ::: "memory");
        }
        f16* tmp = s0; s0 = s1; s1 = s2; s2 = tmp;
    }

    // epilogue: C/D layout col = lane&15, row = (lane>>4)*4 + reg (m89-verified)
    int lk4 = lk << 2;
#pragma unroll
    for (int i = 0; i < 4; ++i) {
#pragma unroll
        for (int rr = 0; rr < 4; ++rr) {
            int row = bm + wm + i * 16 + lk4 + rr;
            size_t moff = (size_t)row * ldc;
#pragma unroll
            for (int j = 0; j < 4; ++j) {
                int col = bn + wn + j * 16 + lr;
                float v = acc[i][j][rr];
                if constexpr (EPI == 0) {
                    ((float*)C)[moff + col] = v + bias[col];
                } else if constexpr (EPI == 1) {
                    ((f16*)C)[moff + col] = (f16)gelu_f(v + bias[col]);
                } else if constexpr (EPI == 2) {
                    ((float*)C)[moff + col] += gamma[col] * (v + bias[col]);
                } else {
                    ((f16*)C)[moff + col] = (f16)(v * bias[col]);
                }
            }
        }
    }
}

// ---------------- head fp32 (stride 1152) -> S fp16 (stride 1088, padded) ----------------
__global__ __launch_bounds__(256) void k_srsi(const float* __restrict__ o,
                                              f16* __restrict__ S) {
    int idx = blockIdx.x * 256 + threadIdx.x;
    if (idx >= BT_ * KI_) return;
    int m = idx / KI_;
    int f2 = idx - m * KI_;
    size_t base = (size_t)m * NPAD_;
    float v = 0.0f;
    if (f2 < NF_) {
        float mag = fminf(__expf(o[base + f2]), 100.0f);
        float sn, cs;
        __sincosf(o[base + NF_ + f2], &sn, &cs);
        v = mag * cs;
    } else if (f2 < NO2_) {
        int f = f2 - NF_;
        float mag = fminf(__expf(o[base + f]), 100.0f);
        float sn, cs;
        __sincosf(o[base + NF_ + f], &sn, &cs);
        v = mag * sn;
    }
    S[idx] = (f16)v;
}

// ---------------- overlap-add + win_env + crop (deterministic gather, f16 frames) ------
__global__ __launch_bounds__(256) void k_gather(const f16* __restrict__ frames,
                                                const float* __restrict__ win,
                                                float* __restrict__ out) {
    int idx = blockIdx.x * 256 + threadIdx.x;
    int b  = idx / LOUT_;
    int lp = idx - b * LOUT_;
    int l = lp + (NFFT_ / 2);
    int thi = l >> 8;
    if (thi > T_ - 1) thi = T_ - 1;
    int tlo = l - (NFFT_ - 1) + (HOP_ - 1);
    tlo = (tlo < 0) ? 0 : (tlo >> 8);
    float num = 0.0f, den = 0.0f;
    for (int t = tlo; t <= thi; ++t) {
        int n = l - (t << 8);
        float wv = win[n];
        num += (float)frames[((size_t)(b * T_ + t) << 10) + n];
        den = fmaf(wv, wv, den);
    }
    out[idx] = num / (den + 1e-11f);
}

// ---------------- launch ----------------
extern "C" void kernel_launch(void* const* d_in, const int* in_sizes, int n_in,
                              void* d_out, int out_size, void* d_ws, size_t ws_size,
                              hipStream_t stream) {
    (void)in_sizes; (void)n_in; (void)out_size; (void)ws_size;
    const float* mel     = (const float*)d_in[0];
    const float* embed_w = (const float*)d_in[1];
    const float* embed_b = (const float*)d_in[2];
    const float* norm_w  = (const float*)d_in[3];
    const float* norm_b  = (const float*)d_in[4];
    const float* bdw = (const float*)d_in[5];
    const float* bdb = (const float*)d_in[6];
    const float* bnw = (const float*)d_in[7];
    const float* bnb = (const float*)d_in[8];
    const float* bw1 = (const float*)d_in[9];
    const float* bb1 = (const float*)d_in[10];
    const float* bw2 = (const float*)d_in[11];
    const float* bb2 = (const float*)d_in[12];
    const float* bg  = (const float*)d_in[13];
    const float* fnw = (const float*)d_in[14];
    const float* fnb = (const float*)d_in[15];
    const float* hw  = (const float*)d_in[16];
    const float* hb  = (const float*)d_in[17];
    const float* win = (const float*)d_in[18];

    char* ws = (char*)d_ws;
    float* xbuf   = (float*)ws;
    f16*   ybuf_h = (f16*)(ws + 33554432);
    f16*   S_h    = (f16*)ws;
    char* R = ws + 50331648;
    f16*   hbuf_h = (f16*)(R + 33554432);
    f16*   A_h    = (f16*)R;
    float* obuf   = (float*)R;
    f16*   frames_h = (f16*)R;
    char* Wr = ws + 134217728;
    f16*   w1_h   = (f16*)Wr;                     // 12,582,912
    f16*   w2_h   = (f16*)(Wr + 12582912);        // 12,582,912
    f16*   head_h = (f16*)(Wr + 25165824);        // 1,179,648
    f16*   wmat_h = (f16*)(Wr + 26345472);        // 2,228,224
    f16*   we_h   = (f16*)(Wr + 28573696);        // 1,376,256
    float* hb_pad = (float*)(Wr + 29949952);      // 4,608
    float* dwT    = (float*)(Wr + 29954560);      // 114,688

    const int nW1 = 8 * H_ * D_;
    k_cvt<<<(nW1 + 255) / 256, 256, 0, stream>>>(bw1, w1_h, nW1);
    k_cvt<<<(nW1 + 255) / 256, 256, 0, stream>>>(bw2, w2_h, nW1);
    k_cvt<<<(CM_ * 7 * D_ + 255) / 256, 256, 0, stream>>>(embed_w, we_h, CM_ * 7 * D_);
    k_cvt_head<<<(NPAD_ * D_ + 255) / 256, 256, 0, stream>>>(hw, head_h);
    k_pad_hb<<<5, 256, 0, stream>>>(hb, hb_pad);
    k_cvtdw<<<(8 * 3584 + 255) / 256, 256, 0, stream>>>(bdw, dwT);
    k_build_wmat<<<(NFFT_ * KI_ + 255) / 256, 256, 0, stream>>>(wmat_h);

    // embed conv as im2col + GEMM
    k_im2col<<<(BT_ * KE_ / 8 + 255) / 256, 256, 0, stream>>>(mel, A_h);
    k_hgemm5<0><<<128 * 4, 256, 0, stream>>>(A_h, we_h, embed_b, nullptr, xbuf,
                                             KE_, D_, 4);
    k_ln<false><<<BT_, 64, 0, stream>>>(xbuf, xbuf, norm_w, norm_b);

    for (int bl = 0; bl < 8; ++bl) {
        k_dwln<<<BT_, 64, 0, stream>>>(xbuf, dwT + bl * 3584, bdb + bl * D_,
                                       bnw + bl * D_, bnb + bl * D_, ybuf_h);
        k_hgemm5<1><<<128 * 12, 256, 0, stream>>>(ybuf_h, w1_h + (size_t)bl * H_ * D_,
                                                  bb1 + bl * H_, nullptr, hbuf_h,
                                                  D_, H_, 12);
        k_hgemm5<2><<<128 * 4, 256, 0, stream>>>(hbuf_h, w2_h + (size_t)bl * D_ * H_,
                                                 bb2 + bl * D_, bg + bl * D_, xbuf,
                                                 H_, D_, 4);
    }

    k_ln<true><<<BT_, 64, 0, stream>>>(xbuf, ybuf_h, fnw, fnb);
    k_hgemm5<0><<<128 * 9, 256, 0, stream>>>(ybuf_h, head_h, hb_pad, nullptr, obuf,
                                             D_, NPAD_, 9);
    k_srsi<<<(BT_ * KI_ + 255) / 256, 256, 0, stream>>>(obuf, S_h);
    k_hgemm5<3><<<128 * 8, 256, 0, stream>>>(S_h, wmat_h, win, nullptr, frames_h,
                                             KI_, NFFT_, 8);
    k_gather<<<B_ * LOUT_ / 256, 256, 0, stream>>>(frames_h, win, (float*)d_out);
}

// Round 8
// 1175.302 us; speedup vs baseline: 1.1699x; 1.0419x over previous
//
#include <hip/hip_runtime.h>
#include <cmath>

#define B_ 8
#define T_ 2048
#define BT_ 16384
#define D_ 512
#define H_ 1536
#define CM_ 192
#define KE_ 1344      // embed K = 192*7 (divisible by 32)
#define TP_ 2054      // padded t-rows per batch in melTp (3 zero pad each side)
#define NFFT_ 1024
#define NF_ 513
#define HOP_ 256
#define NO2_ 1026
#define NPAD_ 1152    // head N padded to tile multiple
#define KI_ 1088      // ISTFT K (= 1026 padded to 32-multiple)
#define LOUT_ 524032

typedef _Float16 f16;
typedef f16 f16x8 __attribute__((ext_vector_type(8)));
typedef float f32x4 __attribute__((ext_vector_type(4)));

// tanh-form GELU: |err| vs exact-erf gelu <= ~3e-4, far under budget
__device__ __forceinline__ float gelu_f(float v) {
    float u = 0.7978845608028654f * v * (1.0f + 0.044715f * v * v);
    float e = __expf(2.0f * u);
    float t = 1.0f - 2.0f * __builtin_amdgcn_rcpf(e + 1.0f);
    return 0.5f * v * (1.0f + t);
}

__device__ __forceinline__ void gload16(const void* g, void* s) {
    __builtin_amdgcn_global_load_lds((const __attribute__((address_space(1))) void*)g,
                                     (__attribute__((address_space(3))) void*)s, 16, 0, 0);
}

// ---------------- conversion / prep kernels ----------------

__global__ __launch_bounds__(256) void k_cvt(const float* __restrict__ src,
                                             f16* __restrict__ dst, int n) {
    int i = blockIdx.x * 256 + threadIdx.x;
    if (i < n) dst[i] = (f16)src[i];
}

// head weights (1026,512) -> fp16 (1152,512) zero-padded rows
__global__ __launch_bounds__(256) void k_cvt_head(const float* __restrict__ src,
                                                  f16* __restrict__ dst) {
    int i = blockIdx.x * 256 + threadIdx.x;
    if (i >= NPAD_ * D_) return;
    int row = i >> 9;
    dst[i] = (row < NO2_) ? (f16)src[i] : (f16)0.0f;
}

__global__ __launch_bounds__(256) void k_pad_hb(const float* __restrict__ src,
                                                float* __restrict__ dst) {
    int i = blockIdx.x * 256 + threadIdx.x;
    if (i < NPAD_) dst[i] = (i < NO2_) ? src[i] : 0.0f;
}

// embed_w (D,Cm,7) -> we_h[d][tap*192 + c]  (tap-major K-order, matches A_h)
__global__ __launch_bounds__(256) void k_cvt_embed(const float* __restrict__ src,
                                                   f16* __restrict__ dst) {
    int i = blockIdx.x * 256 + threadIdx.x;
    if (i >= D_ * KE_) return;
    int d = i / KE_;
    int r2 = i - d * KE_;
    int tap = r2 / CM_;
    int c = r2 - tap * CM_;
    dst[i] = (f16)src[(d * CM_ + c) * 7 + tap];
}

// dw (8,512,7) -> dwT[bl][k][d]
__global__ __launch_bounds__(256) void k_cvtdw(const float* __restrict__ dw,
                                               float* __restrict__ dwT) {
    int i = blockIdx.x * 256 + threadIdx.x;
    if (i >= 8 * 7 * 512) return;
    int bl = i / 3584;
    int rem = i - bl * 3584;
    int k = rem >> 9;
    int d = rem & 511;
    dwT[i] = dw[bl * 3584 + d * 7 + k];
}

// mel (B,Cm,T) fp32 -> melTp[b][tp 0..2053][c 0..191] fp16, tp=t+3, pad rows zero
__global__ __launch_bounds__(256) void k_melT(const float* __restrict__ mel,
                                              f16* __restrict__ mt) {
    int idx = blockIdx.x * 256 + threadIdx.x;   // B_*TP_*24
    if (idx >= B_ * TP_ * 24) return;
    int c8 = idx % 24;
    int rem = idx / 24;
    int tp = rem % TP_;
    int b = rem / TP_;
    int t = tp - 3;
    f16x8 v;
    if (t >= 0 && t < T_) {
        const float* mp = mel + ((size_t)b * CM_ + c8 * 8) * T_ + t;
#pragma unroll
        for (int i = 0; i < 8; ++i) v[i] = (f16)mp[(size_t)i * T_];
    } else {
#pragma unroll
        for (int i = 0; i < 8; ++i) v[i] = (f16)0.0f;
    }
    *(f16x8*)(mt + (size_t)idx * 8) = v;
}

// expand melTp -> A_h: row bt = contiguous 1344 f16 starting at melTp[b][t][0]
__global__ __launch_bounds__(256) void k_expand(const f16* __restrict__ mt,
                                               f16* __restrict__ A) {
    int g = blockIdx.x * 256 + threadIdx.x;    // BT_*168 chunks of 8 f16
    if (g >= BT_ * 168) return;
    int bt = g / 168;
    int k8 = g - bt * 168;
    int b = bt >> 11;
    int t = bt & (T_ - 1);
    f16x8 v = *(const f16x8*)(mt + ((size_t)(b * TP_ + t) * CM_) + k8 * 8);
    *(f16x8*)(A + (size_t)bt * KE_ + k8 * 8) = v;
}

// ISTFT basis fp16: wmat[n][f2], f2<513: cos*scale ; 513..1025: -sin*scale ; pad 0
__global__ __launch_bounds__(256) void k_build_wmat(f16* __restrict__ wmat) {
    int idx = blockIdx.x * 256 + threadIdx.x;
    if (idx >= NFFT_ * KI_) return;
    int n = idx / KI_;
    int f2 = idx - n * KI_;
    float v = 0.0f;
    if (f2 < NF_) {
        int r = (n * f2) & (NFFT_ - 1);
        float sc = (f2 == 0 || f2 == NF_ - 1) ? (1.0f / NFFT_) : (2.0f / NFFT_);
        v = cospif((float)r * (2.0f / NFFT_)) * sc;
    } else if (f2 < NO2_) {
        int f = f2 - NF_;
        int r = (n * f) & (NFFT_ - 1);
        float sc = (f == 0 || f == NF_ - 1) ? (1.0f / NFFT_) : (2.0f / NFFT_);
        v = -sinpif((float)r * (2.0f / NFFT_)) * sc;
    }
    wmat[idx] = (f16)v;
}

// ---------------- LayerNorm over D=512, one wave per row ----------------
template <bool HOUT>
__global__ __launch_bounds__(64) void k_ln(const float* __restrict__ in,
                                           void* __restrict__ out,
                                           const float* __restrict__ w,
                                           const float* __restrict__ b) {
    int row = blockIdx.x;
    int lane = threadIdx.x;
    const float* p = in + (size_t)row * D_ + lane * 8;
    float4 v0 = *(const float4*)p;
    float4 v1 = *(const float4*)(p + 4);
    float s  = v0.x + v0.y + v0.z + v0.w + v1.x + v1.y + v1.z + v1.w;
    float ss = v0.x * v0.x + v0.y * v0.y + v0.z * v0.z + v0.w * v0.w +
               v1.x * v1.x + v1.y * v1.y + v1.z * v1.z + v1.w * v1.w;
#pragma unroll
    for (int off = 32; off > 0; off >>= 1) {
        s  += __shfl_xor(s, off);
        ss += __shfl_xor(ss, off);
    }
    float mean = s * (1.0f / 512.0f);
    float var  = ss * (1.0f / 512.0f) - mean * mean;
    float rs = rsqrtf(var + 1e-5f);
    const float* wp = w + lane * 8;
    const float* bp = b + lane * 8;
    float4 w0 = *(const float4*)wp, w1 = *(const float4*)(wp + 4);
    float4 b0 = *(const float4*)bp, b1 = *(const float4*)(bp + 4);
    float o[8];
    o[0] = (v0.x - mean) * rs * w0.x + b0.x;
    o[1] = (v0.y - mean) * rs * w0.y + b0.y;
    o[2] = (v0.z - mean) * rs * w0.z + b0.z;
    o[3] = (v0.w - mean) * rs * w0.w + b0.w;
    o[4] = (v1.x - mean) * rs * w1.x + b1.x;
    o[5] = (v1.y - mean) * rs * w1.y + b1.y;
    o[6] = (v1.z - mean) * rs * w1.z + b1.z;
    o[7] = (v1.w - mean) * rs * w1.w + b1.w;
    if constexpr (HOUT) {
        f16x8 h;
#pragma unroll
        for (int i = 0; i < 8; ++i) h[i] = (f16)o[i];
        *(f16x8*)((f16*)out + (size_t)row * D_ + lane * 8) = h;
    } else {
        float* q = (float*)out + (size_t)row * D_ + lane * 8;
        *(float4*)q = make_float4(o[0], o[1], o[2], o[3]);
        *(float4*)(q + 4) = make_float4(o[4], o[5], o[6], o[7]);
    }
}

// ---------------- fused depthwise conv (k=7 over t) + LayerNorm -> fp16 ----------------
__global__ __launch_bounds__(64) void k_dwln(const float* __restrict__ x,
                                             const float* __restrict__ dwT,
                                             const float* __restrict__ db,
                                             const float* __restrict__ nw,
                                             const float* __restrict__ nb,
                                             f16* __restrict__ out) {
    int bt = blockIdx.x;
    int t = bt & (T_ - 1);
    int base = bt - t;
    int lane = threadIdx.x;
    int d0 = lane << 3;
    float a[8];
    *(float4*)&a[0] = *(const float4*)(db + d0);
    *(float4*)&a[4] = *(const float4*)(db + d0 + 4);
#pragma unroll
    for (int k = 0; k < 7; ++k) {
        int tt = t + k - 3;
        if (tt < 0 || tt >= T_) continue;
        const float* xp = x + (((size_t)(base + tt)) << 9) + d0;
        float4 x0 = *(const float4*)xp, x1 = *(const float4*)(xp + 4);
        const float* wp = dwT + (k << 9) + d0;
        float4 w0 = *(const float4*)wp, w1 = *(const float4*)(wp + 4);
        a[0] = fmaf(w0.x, x0.x, a[0]); a[1] = fmaf(w0.y, x0.y, a[1]);
        a[2] = fmaf(w0.z, x0.z, a[2]); a[3] = fmaf(w0.w, x0.w, a[3]);
        a[4] = fmaf(w1.x, x1.x, a[4]); a[5] = fmaf(w1.y, x1.y, a[5]);
        a[6] = fmaf(w1.z, x1.z, a[6]); a[7] = fmaf(w1.w, x1.w, a[7]);
    }
    float s = 0.f, ss = 0.f;
#pragma unroll
    for (int i = 0; i < 8; ++i) { s += a[i]; ss = fmaf(a[i], a[i], ss); }
#pragma unroll
    for (int off = 32; off > 0; off >>= 1) {
        s  += __shfl_xor(s, off);
        ss += __shfl_xor(ss, off);
    }
    float mean = s * (1.0f / 512.0f);
    float var  = ss * (1.0f / 512.0f) - mean * mean;
    float rs = rsqrtf(var + 1e-5f);
    float4 w0 = *(const float4*)(nw + d0), w1 = *(const float4*)(nw + d0 + 4);
    float4 b0 = *(const float4*)(nb + d0), b1 = *(const float4*)(nb + d0 + 4);
    f16x8 h;
    h[0] = (f16)((a[0] - mean) * rs * w0.x + b0.x);
    h[1] = (f16)((a[1] - mean) * rs * w0.y + b0.y);
    h[2] = (f16)((a[2] - mean) * rs * w0.z + b0.z);
    h[3] = (f16)((a[3] - mean) * rs * w0.w + b0.w);
    h[4] = (f16)((a[4] - mean) * rs * w1.x + b1.x);
    h[5] = (f16)((a[5] - mean) * rs * w1.y + b1.y);
    h[6] = (f16)((a[6] - mean) * rs * w1.z + b1.z);
    h[7] = (f16)((a[7] - mean) * rs * w1.w + b1.w);
    *(f16x8*)(out + ((size_t)bt << 9) + d0) = h;
}

// ---- fp16 MFMA GEMM v5 (r6-proven, byte-identical): 128x128, BK=32, 3-ring, vmcnt(4) ----
#define TSZ_ 4096   // f16 elems per matrix tile (128x32)

__device__ __forceinline__ void stage32(const f16* __restrict__ g, f16* s,
                                        int K, int kof, int tid) {
    int dr0 = tid >> 3;        // 0..31
    int sl  = tid & 7;
#pragma unroll
    for (int i = 0; i < 2; ++i) {
        int d  = dr0 + (i << 5);           // double-row 0..63
        int gs = sl ^ (d & 7);             // pre-swizzled global slot
        int row = (d << 1) + (gs >> 2);
        int kc  = gs & 3;
        gload16(g + (size_t)row * K + kof + (kc << 3),
                s + (d << 6) + (sl << 3)); // linear dest: wave base + lane*16B
    }
}

#define MF(d, a, b) d = __builtin_amdgcn_mfma_f32_16x16x32_f16(a, b, d, 0, 0, 0)

template <int EPI>
__global__ __launch_bounds__(256, 3) void k_hgemm5(const f16* __restrict__ A,
                                                   const f16* __restrict__ W,
                                                   const float* __restrict__ bias,
                                                   const float* __restrict__ gamma,
                                                   void* __restrict__ C,
                                                   int K, int ldc, int nNt) {
    __shared__ f16 lds[3 * 2 * TSZ_];
    int tid = threadIdx.x;
    int nwg = gridDim.x, bid = blockIdx.x;
    int q = nwg >> 3, r = nwg & 7;
    int xcd = bid & 7, lin = bid >> 3;
    int swz = (xcd < r ? xcd * (q + 1) : r * (q + 1) + (xcd - r) * q) + lin;
    int bm = (swz / nNt) << 7;
    int bn = (swz % nNt) << 7;
    const f16* gA = A + (size_t)bm * K;
    const f16* gW = W + (size_t)bn * K;

    int l = tid & 63;
    int wv = tid >> 6;
    int wm = (wv & 1) << 6;    // 2 wave-rows of 64
    int wn = (wv >> 1) << 6;   // 2 wave-cols of 64
    int lr = l & 15;
    int lk = l >> 4;
    int lrh = lr >> 1;
    int s0l = ((lr & 1) << 2) | lk;   // logical slot for this lane's (row-half, chunk)

    // loop-invariant read offsets (f16 units)
    int offA[4], offB[4];
#pragma unroll
    for (int i = 0; i < 4; ++i) {
        int dA = (wm >> 1) + i * 8 + lrh;
        offA[i] = (dA << 6) + ((s0l ^ (dA & 7)) << 3);
        int dB = (wn >> 1) + i * 8 + lrh;
        offB[i] = (dB << 6) + ((s0l ^ (dB & 7)) << 3);
    }

    f32x4 acc[4][4];
#pragma unroll
    for (int i = 0; i < 4; ++i)
#pragma unroll
        for (int j = 0; j < 4; ++j) acc[i][j] = {0.f, 0.f, 0.f, 0.f};

    int nk = K >> 5;
    f16* s0 = lds;
    f16* s1 = lds + 2 * TSZ_;
    f16* s2 = lds + 4 * TSZ_;

    // prologue: stage tiles 0,1 (8 loads); wait for tile 0 (4 outstanding allowed)
    stage32(gA, s0, K, 0, tid);        stage32(gW, s0 + TSZ_, K, 0, tid);
    stage32(gA, s1, K, 32, tid);       stage32(gW, s1 + TSZ_, K, 32, tid);
    asm volatile("s_waitcnt vmcnt(4)" ::: "memory");
    __builtin_amdgcn_s_barrier();

    for (int t = 0; t < nk; ++t) {
        bool stg = (t + 2 < nk);
        if (stg) {
            int ko = (t + 2) << 5;
            stage32(gA, s2, K, ko, tid);
            stage32(gW, s2 + TSZ_, K, ko, tid);
        }
        f16x8 af[4], bf[4];
#pragma unroll
        for (int i = 0; i < 4; ++i) af[i] = *(const f16x8*)(s0 + offA[i]);
#pragma unroll
        for (int j = 0; j < 4; ++j) bf[j] = *(const f16x8*)(s0 + TSZ_ + offB[j]);
        __builtin_amdgcn_s_setprio(1);
#pragma unroll
        for (int i = 0; i < 4; ++i)
#pragma unroll
            for (int j = 0; j < 4; ++j) MF(acc[i][j], af[i], bf[j]);
        __builtin_amdgcn_s_setprio(0);
        if (stg)               asm volatile("s_waitcnt vmcnt(4)" ::: "memory");
        else if (t + 1 < nk)   asm volatile("s_waitcnt vmcnt(0)" ::: "memory");
        if (t + 1 < nk) {
            __builtin_amdgcn_s_barrier();
            asm volatile("" ::: "memory");
        }
        f16* tmp = s0; s0 = s1; s1 = s2; s2 = tmp;
    }

    // epilogue: C/D layout col = lane&15, row = (lane>>4)*4 + reg (m89-verified)
    int lk4 = lk << 2;
#pragma unroll
    for (int i = 0; i < 4; ++i) {
#pragma unroll
        for (int rr = 0; rr < 4; ++rr) {
            int row = bm + wm + i * 16 + lk4 + rr;
            size_t moff = (size_t)row * ldc;
#pragma unroll
            for (int j = 0; j < 4; ++j) {
                int col = bn + wn + j * 16 + lr;
                float v = acc[i][j][rr];
                if constexpr (EPI == 0) {
                    ((float*)C)[moff + col] = v + bias[col];
                } else if constexpr (EPI == 1) {
                    ((f16*)C)[moff + col] = (f16)gelu_f(v + bias[col]);
                } else if constexpr (EPI == 2) {
                    ((float*)C)[moff + col] += gamma[col] * (v + bias[col]);
                } else {
                    ((f16*)C)[moff + col] = (f16)(v * bias[col]);
                }
            }
        }
    }
}

// ---------------- head fp32 (stride 1152) -> S fp16 (stride 1088, padded) ----------------
__global__ __launch_bounds__(256) void k_srsi(const float* __restrict__ o,
                                              f16* __restrict__ S) {
    int idx = blockIdx.x * 256 + threadIdx.x;
    if (idx >= BT_ * KI_) return;
    int m = idx / KI_;
    int f2 = idx - m * KI_;
    size_t base = (size_t)m * NPAD_;
    float v = 0.0f;
    if (f2 < NF_) {
        float mag = fminf(__expf(o[base + f2]), 100.0f);
        float sn, cs;
        __sincosf(o[base + NF_ + f2], &sn, &cs);
        v = mag * cs;
    } else if (f2 < NO2_) {
        int f = f2 - NF_;
        float mag = fminf(__expf(o[base + f]), 100.0f);
        float sn, cs;
        __sincosf(o[base + NF_ + f], &sn, &cs);
        v = mag * sn;
    }
    S[idx] = (f16)v;
}

// ---------------- overlap-add + win_env + crop (deterministic gather, f16 frames) ------
__global__ __launch_bounds__(256) void k_gather(const f16* __restrict__ frames,
                                                const float* __restrict__ win,
                                                float* __restrict__ out) {
    int idx = blockIdx.x * 256 + threadIdx.x;
    int b  = idx / LOUT_;
    int lp = idx - b * LOUT_;
    int l = lp + (NFFT_ / 2);
    int thi = l >> 8;
    if (thi > T_ - 1) thi = T_ - 1;
    int tlo = l - (NFFT_ - 1) + (HOP_ - 1);
    tlo = (tlo < 0) ? 0 : (tlo >> 8);
    float num = 0.0f, den = 0.0f;
    for (int t = tlo; t <= thi; ++t) {
        int n = l - (t << 8);
        float wv = win[n];
        num += (float)frames[((size_t)(b * T_ + t) << 10) + n];
        den = fmaf(wv, wv, den);
    }
    out[idx] = num / (den + 1e-11f);
}

// ---------------- launch ----------------
extern "C" void kernel_launch(void* const* d_in, const int* in_sizes, int n_in,
                              void* d_out, int out_size, void* d_ws, size_t ws_size,
                              hipStream_t stream) {
    (void)in_sizes; (void)n_in; (void)out_size; (void)ws_size;
    const float* mel     = (const float*)d_in[0];
    const float* embed_w = (const float*)d_in[1];
    const float* embed_b = (const float*)d_in[2];
    const float* norm_w  = (const float*)d_in[3];
    const float* norm_b  = (const float*)d_in[4];
    const float* bdw = (const float*)d_in[5];
    const float* bdb = (const float*)d_in[6];
    const float* bnw = (const float*)d_in[7];
    const float* bnb = (const float*)d_in[8];
    const float* bw1 = (const float*)d_in[9];
    const float* bb1 = (const float*)d_in[10];
    const float* bw2 = (const float*)d_in[11];
    const float* bb2 = (const float*)d_in[12];
    const float* bg  = (const float*)d_in[13];
    const float* fnw = (const float*)d_in[14];
    const float* fnb = (const float*)d_in[15];
    const float* hw  = (const float*)d_in[16];
    const float* hb  = (const float*)d_in[17];
    const float* win = (const float*)d_in[18];

    char* ws = (char*)d_ws;
    // region A: [0, 50.3MB): xbuf fp32 + ybuf_h fp16; melTp transiently at base (dead
    // once embed GEMM writes xbuf); S_h overlays later
    float* xbuf   = (float*)ws;
    f16*   melTp  = (f16*)ws;                     // 6,309,888 B, dead after k_expand+embed
    f16*   ybuf_h = (f16*)(ws + 33554432);
    f16*   S_h    = (f16*)ws;
    // region R: [50.3MB, 134.2MB): A_h / obuf / frames_h at base; hbuf_h at +33.5MB
    char* R = ws + 50331648;
    f16*   hbuf_h = (f16*)(R + 33554432);
    f16*   A_h    = (f16*)R;
    float* obuf   = (float*)R;
    f16*   frames_h = (f16*)R;
    // region W: [134.2MB, ...): converted weights (r6-proven envelope)
    char* Wr = ws + 134217728;
    f16*   w1_h   = (f16*)Wr;                     // 12,582,912
    f16*   w2_h   = (f16*)(Wr + 12582912);        // 12,582,912
    f16*   head_h = (f16*)(Wr + 25165824);        // 1,179,648
    f16*   wmat_h = (f16*)(Wr + 26345472);        // 2,228,224
    f16*   we_h   = (f16*)(Wr + 28573696);        // 1,376,256
    float* hb_pad = (float*)(Wr + 29949952);      // 4,608
    float* dwT    = (float*)(Wr + 29954560);      // 114,688

    const int nW1 = 8 * H_ * D_;
    k_cvt<<<(nW1 + 255) / 256, 256, 0, stream>>>(bw1, w1_h, nW1);
    k_cvt<<<(nW1 + 255) / 256, 256, 0, stream>>>(bw2, w2_h, nW1);
    k_cvt_embed<<<(D_ * KE_ + 255) / 256, 256, 0, stream>>>(embed_w, we_h);
    k_cvt_head<<<(NPAD_ * D_ + 255) / 256, 256, 0, stream>>>(hw, head_h);
    k_pad_hb<<<5, 256, 0, stream>>>(hb, hb_pad);
    k_cvtdw<<<(8 * 3584 + 255) / 256, 256, 0, stream>>>(bdw, dwT);
    k_build_wmat<<<(NFFT_ * KI_ + 255) / 256, 256, 0, stream>>>(wmat_h);

    // embed conv: mel -> melTp (fp16 t-major) -> A_h (im2col via contiguous row copies)
    k_melT<<<(B_ * TP_ * 24 + 255) / 256, 256, 0, stream>>>(mel, melTp);
    k_expand<<<(BT_ * 168 + 255) / 256, 256, 0, stream>>>(melTp, A_h);
    k_hgemm5<0><<<128 * 4, 256, 0, stream>>>(A_h, we_h, embed_b, nullptr, xbuf,
                                             KE_, D_, 4);
    k_ln<false><<<BT_, 64, 0, stream>>>(xbuf, xbuf, norm_w, norm_b);

    for (int bl = 0; bl < 8; ++bl) {
        k_dwln<<<BT_, 64, 0, stream>>>(xbuf, dwT + bl * 3584, bdb + bl * D_,
                                       bnw + bl * D_, bnb + bl * D_, ybuf_h);
        k_hgemm5<1><<<128 * 12, 256, 0, stream>>>(ybuf_h, w1_h + (size_t)bl * H_ * D_,
                                                  bb1 + bl * H_, nullptr, hbuf_h,
                                                  D_, H_, 12);
        k_hgemm5<2><<<128 * 4, 256, 0, stream>>>(hbuf_h, w2_h + (size_t)bl * D_ * H_,
                                                 bb2 + bl * D_, bg + bl * D_, xbuf,
                                                 H_, D_, 4);
    }

    k_ln<true><<<BT_, 64, 0, stream>>>(xbuf, ybuf_h, fnw, fnb);
    k_hgemm5<0><<<128 * 9, 256, 0, stream>>>(ybuf_h, head_h, hb_pad, nullptr, obuf,
                                             D_, NPAD_, 9);
    k_srsi<<<(BT_ * KI_ + 255) / 256, 256, 0, stream>>>(obuf, S_h);
    k_hgemm5<3><<<128 * 8, 256, 0, stream>>>(S_h, wmat_h, win, nullptr, frames_h,
                                             KI_, NFFT_, 8);
    k_gather<<<B_ * LOUT_ / 256, 256, 0, stream>>>(frames_h, win, (float*)d_out);
}

// Round 10
// 1026.403 us; speedup vs baseline: 1.3396x; 1.1451x over previous
//
#include <hip/hip_runtime.h>
#include <cmath>

#define B_ 8
#define T_ 2048
#define BT_ 16384
#define D_ 512
#define H_ 1536
#define CM_ 192
#define KE_ 1344      // embed K = 192*7 (divisible by 32)
#define TP_ 2054      // padded t-rows per batch in melTp (3 zero pad each side)
#define NFFT_ 1024
#define NF_ 513
#define HOP_ 256
#define NO2_ 1026
#define NPAD_ 1152    // head N padded to tile multiple
#define KI_ 1088      // ISTFT K (= 1026 padded to 32-multiple)
#define LOUT_ 524032

typedef _Float16 f16;
typedef f16 f16x8 __attribute__((ext_vector_type(8)));
typedef float f32x4 __attribute__((ext_vector_type(4)));

// tanh-form GELU: |err| vs exact-erf gelu <= ~3e-4, far under budget
__device__ __forceinline__ float gelu_f(float v) {
    float u = 0.7978845608028654f * v * (1.0f + 0.044715f * v * v);
    float e = __expf(2.0f * u);
    float t = 1.0f - 2.0f * __builtin_amdgcn_rcpf(e + 1.0f);
    return 0.5f * v * (1.0f + t);
}

__device__ __forceinline__ void gload16(const void* g, void* s) {
    __builtin_amdgcn_global_load_lds((const __attribute__((address_space(1))) void*)g,
                                     (__attribute__((address_space(3))) void*)s, 16, 0, 0);
}

// ---------------- conversion / prep kernels ----------------

__global__ __launch_bounds__(256) void k_cvt(const float* __restrict__ src,
                                             f16* __restrict__ dst, int n) {
    int i = blockIdx.x * 256 + threadIdx.x;
    if (i < n) dst[i] = (f16)src[i];
}

// head weights (1026,512) -> fp16 (1152,512) zero-padded rows
__global__ __launch_bounds__(256) void k_cvt_head(const float* __restrict__ src,
                                                  f16* __restrict__ dst) {
    int i = blockIdx.x * 256 + threadIdx.x;
    if (i >= NPAD_ * D_) return;
    int row = i >> 9;
    dst[i] = (row < NO2_) ? (f16)src[i] : (f16)0.0f;
}

__global__ __launch_bounds__(256) void k_pad_hb(const float* __restrict__ src,
                                                float* __restrict__ dst) {
    int i = blockIdx.x * 256 + threadIdx.x;
    if (i < NPAD_) dst[i] = (i < NO2_) ? src[i] : 0.0f;
}

// embed_w (D,Cm,7) -> we_h[d][tap*192 + c]  (tap-major K-order, matches A_h)
__global__ __launch_bounds__(256) void k_cvt_embed(const float* __restrict__ src,
                                                   f16* __restrict__ dst) {
    int i = blockIdx.x * 256 + threadIdx.x;
    if (i >= D_ * KE_) return;
    int d = i / KE_;
    int r2 = i - d * KE_;
    int tap = r2 / CM_;
    int c = r2 - tap * CM_;
    dst[i] = (f16)src[(d * CM_ + c) * 7 + tap];
}

// dw (8,512,7) -> dwT[bl][k][d]
__global__ __launch_bounds__(256) void k_cvtdw(const float* __restrict__ dw,
                                               float* __restrict__ dwT) {
    int i = blockIdx.x * 256 + threadIdx.x;
    if (i >= 8 * 7 * 512) return;
    int bl = i / 3584;
    int rem = i - bl * 3584;
    int k = rem >> 9;
    int d = rem & 511;
    dwT[i] = dw[bl * 3584 + d * 7 + k];
}

// mel (B,Cm,T) fp32 -> melTp[b][tp 0..2053][c 0..191] fp16, tp=t+3, pad rows zero
__global__ __launch_bounds__(256) void k_melT(const float* __restrict__ mel,
                                              f16* __restrict__ mt) {
    int idx = blockIdx.x * 256 + threadIdx.x;   // B_*TP_*24
    if (idx >= B_ * TP_ * 24) return;
    int c8 = idx % 24;
    int rem = idx / 24;
    int tp = rem % TP_;
    int b = rem / TP_;
    int t = tp - 3;
    f16x8 v;
    if (t >= 0 && t < T_) {
        const float* mp = mel + ((size_t)b * CM_ + c8 * 8) * T_ + t;
#pragma unroll
        for (int i = 0; i < 8; ++i) v[i] = (f16)mp[(size_t)i * T_];
    } else {
#pragma unroll
        for (int i = 0; i < 8; ++i) v[i] = (f16)0.0f;
    }
    *(f16x8*)(mt + (size_t)idx * 8) = v;
}

// expand melTp -> A_h: row bt = contiguous 1344 f16 starting at melTp[b][t][0]
__global__ __launch_bounds__(256) void k_expand(const f16* __restrict__ mt,
                                               f16* __restrict__ A) {
    int g = blockIdx.x * 256 + threadIdx.x;    // BT_*168 chunks of 8 f16
    if (g >= BT_ * 168) return;
    int bt = g / 168;
    int k8 = g - bt * 168;
    int b = bt >> 11;
    int t = bt & (T_ - 1);
    f16x8 v = *(const f16x8*)(mt + ((size_t)(b * TP_ + t) * CM_) + k8 * 8);
    *(f16x8*)(A + (size_t)bt * KE_ + k8 * 8) = v;
}

// ISTFT basis fp16: wmat[n][f2], f2<513: cos*scale ; 513..1025: -sin*scale ; pad 0
__global__ __launch_bounds__(256) void k_build_wmat(f16* __restrict__ wmat) {
    int idx = blockIdx.x * 256 + threadIdx.x;
    if (idx >= NFFT_ * KI_) return;
    int n = idx / KI_;
    int f2 = idx - n * KI_;
    float v = 0.0f;
    if (f2 < NF_) {
        int r = (n * f2) & (NFFT_ - 1);
        float sc = (f2 == 0 || f2 == NF_ - 1) ? (1.0f / NFFT_) : (2.0f / NFFT_);
        v = cospif((float)r * (2.0f / NFFT_)) * sc;
    } else if (f2 < NO2_) {
        int f = f2 - NF_;
        int r = (n * f) & (NFFT_ - 1);
        float sc = (f == 0 || f == NF_ - 1) ? (1.0f / NFFT_) : (2.0f / NFFT_);
        v = -sinpif((float)r * (2.0f / NFFT_)) * sc;
    }
    wmat[idx] = (f16)v;
}

// ---------------- LayerNorm over D=512, one wave per row ----------------
template <bool HOUT>
__global__ __launch_bounds__(64) void k_ln(const float* __restrict__ in,
                                           void* __restrict__ out,
                                           const float* __restrict__ w,
                                           const float* __restrict__ b) {
    int row = blockIdx.x;
    int lane = threadIdx.x;
    const float* p = in + (size_t)row * D_ + lane * 8;
    float4 v0 = *(const float4*)p;
    float4 v1 = *(const float4*)(p + 4);
    float s  = v0.x + v0.y + v0.z + v0.w + v1.x + v1.y + v1.z + v1.w;
    float ss = v0.x * v0.x + v0.y * v0.y + v0.z * v0.z + v0.w * v0.w +
               v1.x * v1.x + v1.y * v1.y + v1.z * v1.z + v1.w * v1.w;
#pragma unroll
    for (int off = 32; off > 0; off >>= 1) {
        s  += __shfl_xor(s, off);
        ss += __shfl_xor(ss, off);
    }
    float mean = s * (1.0f / 512.0f);
    float var  = ss * (1.0f / 512.0f) - mean * mean;
    float rs = rsqrtf(var + 1e-5f);
    const float* wp = w + lane * 8;
    const float* bp = b + lane * 8;
    float4 w0 = *(const float4*)wp, w1 = *(const float4*)(wp + 4);
    float4 b0 = *(const float4*)bp, b1 = *(const float4*)(bp + 4);
    float o[8];
    o[0] = (v0.x - mean) * rs * w0.x + b0.x;
    o[1] = (v0.y - mean) * rs * w0.y + b0.y;
    o[2] = (v0.z - mean) * rs * w0.z + b0.z;
    o[3] = (v0.w - mean) * rs * w0.w + b0.w;
    o[4] = (v1.x - mean) * rs * w1.x + b1.x;
    o[5] = (v1.y - mean) * rs * w1.y + b1.y;
    o[6] = (v1.z - mean) * rs * w1.z + b1.z;
    o[7] = (v1.w - mean) * rs * w1.w + b1.w;
    if constexpr (HOUT) {
        f16x8 h;
#pragma unroll
        for (int i = 0; i < 8; ++i) h[i] = (f16)o[i];
        *(f16x8*)((f16*)out + (size_t)row * D_ + lane * 8) = h;
    } else {
        float* q = (float*)out + (size_t)row * D_ + lane * 8;
        *(float4*)q = make_float4(o[0], o[1], o[2], o[3]);
        *(float4*)(q + 4) = make_float4(o[4], o[5], o[6], o[7]);
    }
}

// ---- fused depthwise conv + LayerNorm, t-tiled via LDS (1.37x read amp vs 7x) ----
// One block = 16 output t-rows x D=512 for one batch; stages 22 rows (halo 3+3)
// into LDS once. Wave `slot` (tid>>6) owns rows t0+slot*4+u (u=0..3); LN reduce is
// the proven 64-lane shfl_xor pattern. LDS reads: 64 lanes span 512 consecutive
// floats (2 lanes/bank = free, m136). 45KB LDS -> 3 blocks/CU.
__global__ __launch_bounds__(256) void k_dwln2(const float* __restrict__ x,
                                               const float* __restrict__ dwT,
                                               const float* __restrict__ db,
                                               const float* __restrict__ nw,
                                               const float* __restrict__ nb,
                                               f16* __restrict__ out) {
    __shared__ float xs[22][512];
    int tid = threadIdx.x;
    int blk = blockIdx.x;            // b*128 + tc
    int b = blk >> 7;
    int t0 = (blk & 127) << 4;
    const float* xb = x + ((size_t)b << 20);   // b * T_ * D_
#pragma unroll
    for (int i = 0; i < 11; ++i) {
        int idx = tid + (i << 8);    // float4 index over 22*128
        int row = idx >> 7;
        int c4 = idx & 127;
        int t = t0 + row - 3;
        float4 v = make_float4(0.f, 0.f, 0.f, 0.f);
        if (t >= 0 && t < T_) v = *(const float4*)(xb + ((size_t)t << 9) + (c4 << 2));
        *(float4*)&xs[row][c4 << 2] = v;
    }
    __syncthreads();

    int o = tid & 63;          // d-octet
    int slot = tid >> 6;       // wave id = t-group
    int d0 = o << 3;
    float acc[4][8];
    {
        float4 b0 = *(const float4*)(db + d0);
        float4 b1 = *(const float4*)(db + d0 + 4);
#pragma unroll
        for (int u = 0; u < 4; ++u) {
            acc[u][0] = b0.x; acc[u][1] = b0.y; acc[u][2] = b0.z; acc[u][3] = b0.w;
            acc[u][4] = b1.x; acc[u][5] = b1.y; acc[u][6] = b1.z; acc[u][7] = b1.w;
        }
    }
#pragma unroll
    for (int k = 0; k < 7; ++k) {
        float w8[8];
        *(float4*)&w8[0] = *(const float4*)(dwT + (k << 9) + d0);
        *(float4*)&w8[4] = *(const float4*)(dwT + (k << 9) + d0 + 4);
#pragma unroll
        for (int u = 0; u < 4; ++u) {
            int row = (slot << 2) + u + k;   // t_local + k, in [0,21]
            float x8[8];
            *(float4*)&x8[0] = *(const float4*)&xs[row][d0];
            *(float4*)&x8[4] = *(const float4*)&xs[row][d0 + 4];
#pragma unroll
            for (int i = 0; i < 8; ++i) acc[u][i] = fmaf(w8[i], x8[i], acc[u][i]);
        }
    }
    float4 w0 = *(const float4*)(nw + d0), w1 = *(const float4*)(nw + d0 + 4);
    float4 n0 = *(const float4*)(nb + d0), n1 = *(const float4*)(nb + d0 + 4);
    float nwv[8] = {w0.x, w0.y, w0.z, w0.w, w1.x, w1.y, w1.z, w1.w};
    float nbv[8] = {n0.x, n0.y, n0.z, n0.w, n1.x, n1.y, n1.z, n1.w};
#pragma unroll
    for (int u = 0; u < 4; ++u) {
        float s = 0.f, ss = 0.f;
#pragma unroll
        for (int i = 0; i < 8; ++i) { s += acc[u][i]; ss = fmaf(acc[u][i], acc[u][i], ss); }
#pragma unroll
        for (int off = 32; off > 0; off >>= 1) {
            s  += __shfl_xor(s, off);
            ss += __shfl_xor(ss, off);
        }
        float mean = s * (1.0f / 512.0f);
        float var  = ss * (1.0f / 512.0f) - mean * mean;
        float rs = rsqrtf(var + 1e-5f);
        f16x8 h;
#pragma unroll
        for (int i = 0; i < 8; ++i)
            h[i] = (f16)((acc[u][i] - mean) * rs * nwv[i] + nbv[i]);
        int t = t0 + (slot << 2) + u;
        *(f16x8*)(out + (((size_t)(b << 11) + t) << 9) + d0) = h;
    }
}

// ---- fp16 MFMA GEMM v5 (r6/r8-proven, byte-identical): 128x128, BK=32, 3-ring, vmcnt(4) ----
#define TSZ_ 4096   // f16 elems per matrix tile (128x32)

__device__ __forceinline__ void stage32(const f16* __restrict__ g, f16* s,
                                        int K, int kof, int tid) {
    int dr0 = tid >> 3;        // 0..31
    int sl  = tid & 7;
#pragma unroll
    for (int i = 0; i < 2; ++i) {
        int d  = dr0 + (i << 5);           // double-row 0..63
        int gs = sl ^ (d & 7);             // pre-swizzled global slot
        int row = (d << 1) + (gs >> 2);
        int kc  = gs & 3;
        gload16(g + (size_t)row * K + kof + (kc << 3),
                s + (d << 6) + (sl << 3)); // linear dest: wave base + lane*16B
    }
}

#define MF(d, a, b) d = __builtin_amdgcn_mfma_f32_16x16x32_f16(a, b, d, 0, 0, 0)

template <int EPI>
__global__ __launch_bounds__(256, 3) void k_hgemm5(const f16* __restrict__ A,
                                                   const f16* __restrict__ W,
                                                   const float* __restrict__ bias,
                                                   const float* __restrict__ gamma,
                                                   void* __restrict__ C,
                                                   int K, int ldc, int nNt) {
    __shared__ f16 lds[3 * 2 * TSZ_];
    int tid = threadIdx.x;
    int nwg = gridDim.x, bid = blockIdx.x;
    int q = nwg >> 3, r = nwg & 7;
    int xcd = bid & 7, lin = bid >> 3;
    int swz = (xcd < r ? xcd * (q + 1) : r * (q + 1) + (xcd - r) * q) + lin;
    int bm = (swz / nNt) << 7;
    int bn = (swz % nNt) << 7;
    const f16* gA = A + (size_t)bm * K;
    const f16* gW = W + (size_t)bn * K;

    int l = tid & 63;
    int wv = tid >> 6;
    int wm = (wv & 1) << 6;    // 2 wave-rows of 64
    int wn = (wv >> 1) << 6;   // 2 wave-cols of 64
    int lr = l & 15;
    int lk = l >> 4;
    int lrh = lr >> 1;
    int s0l = ((lr & 1) << 2) | lk;   // logical slot for this lane's (row-half, chunk)

    // loop-invariant read offsets (f16 units)
    int offA[4], offB[4];
#pragma unroll
    for (int i = 0; i < 4; ++i) {
        int dA = (wm >> 1) + i * 8 + lrh;
        offA[i] = (dA << 6) + ((s0l ^ (dA & 7)) << 3);
        int dB = (wn >> 1) + i * 8 + lrh;
        offB[i] = (dB << 6) + ((s0l ^ (dB & 7)) << 3);
    }

    f32x4 acc[4][4];
#pragma unroll
    for (int i = 0; i < 4; ++i)
#pragma unroll
        for (int j = 0; j < 4; ++j) acc[i][j] = {0.f, 0.f, 0.f, 0.f};

    int nk = K >> 5;
    f16* s0 = lds;
    f16* s1 = lds + 2 * TSZ_;
    f16* s2 = lds + 4 * TSZ_;

    // prologue: stage tiles 0,1 (8 loads); wait for tile 0 (4 outstanding allowed)
    stage32(gA, s0, K, 0, tid);        stage32(gW, s0 + TSZ_, K, 0, tid);
    stage32(gA, s1, K, 32, tid);       stage32(gW, s1 + TSZ_, K, 32, tid);
    asm volatile("s_waitcnt vmcnt(4)" ::: "memory");
    __builtin_amdgcn_s_barrier();

    for (int t = 0; t < nk; ++t) {
        bool stg = (t + 2 < nk);
        if (stg) {
            int ko = (t + 2) << 5;
            stage32(gA, s2, K, ko, tid);
            stage32(gW, s2 + TSZ_, K, ko, tid);
        }
        f16x8 af[4], bf[4];
#pragma unroll
        for (int i = 0; i < 4; ++i) af[i] = *(const f16x8*)(s0 + offA[i]);
#pragma unroll
        for (int j = 0; j < 4; ++j) bf[j] = *(const f16x8*)(s0 + TSZ_ + offB[j]);
        __builtin_amdgcn_s_setprio(1);
#pragma unroll
        for (int i = 0; i < 4; ++i)
#pragma unroll
            for (int j = 0; j < 4; ++j) MF(acc[i][j], af[i], bf[j]);
        __builtin_amdgcn_s_setprio(0);
        if (stg)               asm volatile("s_waitcnt vmcnt(4)" ::: "memory");
        else if (t + 1 < nk)   asm volatile("s_waitcnt vmcnt(0)" ::: "memory");
        if (t + 1 < nk) {
            __builtin_amdgcn_s_barrier();
            asm volatile("" ::: "memory");
        }
        f16* tmp = s0; s0 = s1; s1 = s2; s2 = tmp;
    }

    // epilogue: C/D layout col = lane&15, row = (lane>>4)*4 + reg (m89-verified)
    int lk4 = lk << 2;
#pragma unroll
    for (int i = 0; i < 4; ++i) {
#pragma unroll
        for (int rr = 0; rr < 4; ++rr) {
            int row = bm + wm + i * 16 + lk4 + rr;
            size_t moff = (size_t)row * ldc;
#pragma unroll
            for (int j = 0; j < 4; ++j) {
                int col = bn + wn + j * 16 + lr;
                float v = acc[i][j][rr];
                if constexpr (EPI == 0) {
                    ((float*)C)[moff + col] = v + bias[col];
                } else if constexpr (EPI == 1) {
                    ((f16*)C)[moff + col] = (f16)gelu_f(v + bias[col]);
                } else if constexpr (EPI == 2) {
                    ((float*)C)[moff + col] += gamma[col] * (v + bias[col]);
                } else {
                    ((f16*)C)[moff + col] = (f16)(v * bias[col]);
                }
            }
        }
    }
}

// ---------------- head fp32 (stride 1152) -> S fp16 (stride 1088, padded) ----------------
__global__ __launch_bounds__(256) void k_srsi(const float* __restrict__ o,
                                              f16* __restrict__ S) {
    int idx = blockIdx.x * 256 + threadIdx.x;
    if (idx >= BT_ * KI_) return;
    int m = idx / KI_;
    int f2 = idx - m * KI_;
    size_t base = (size_t)m * NPAD_;
    float v = 0.0f;
    if (f2 < NF_) {
        float mag = fminf(__expf(o[base + f2]), 100.0f);
        float sn, cs;
        __sincosf(o[base + NF_ + f2], &sn, &cs);
        v = mag * cs;
    } else if (f2 < NO2_) {
        int f = f2 - NF_;
        float mag = fminf(__expf(o[base + f]), 100.0f);
        float sn, cs;
        __sincosf(o[base + NF_ + f], &sn, &cs);
        v = mag * sn;
    }
    S[idx] = (f16)v;
}

// ---------------- overlap-add + win_env + crop (deterministic gather, f16 frames) ------
__global__ __launch_bounds__(256) void k_gather(const f16* __restrict__ frames,
                                                const float* __restrict__ win,
                                                float* __restrict__ out) {
    int idx = blockIdx.x * 256 + threadIdx.x;
    int b  = idx / LOUT_;
    int lp = idx - b * LOUT_;
    int l = lp + (NFFT_ / 2);
    int thi = l >> 8;
    if (thi > T_ - 1) thi = T_ - 1;
    int tlo = l - (NFFT_ - 1) + (HOP_ - 1);
    tlo = (tlo < 0) ? 0 : (tlo >> 8);
    float num = 0.0f, den = 0.0f;
    for (int t = tlo; t <= thi; ++t) {
        int n = l - (t << 8);
        float wv = win[n];
        num += (float)frames[((size_t)(b * T_ + t) << 10) + n];
        den = fmaf(wv, wv, den);
    }
    out[idx] = num / (den + 1e-11f);
}

// ---------------- launch ----------------
extern "C" void kernel_launch(void* const* d_in, const int* in_sizes, int n_in,
                              void* d_out, int out_size, void* d_ws, size_t ws_size,
                              hipStream_t stream) {
    (void)in_sizes; (void)n_in; (void)out_size; (void)ws_size;
    const float* mel     = (const float*)d_in[0];
    const float* embed_w = (const float*)d_in[1];
    const float* embed_b = (const float*)d_in[2];
    const float* norm_w  = (const float*)d_in[3];
    const float* norm_b  = (const float*)d_in[4];
    const float* bdw = (const float*)d_in[5];
    const float* bdb = (const float*)d_in[6];
    const float* bnw = (const float*)d_in[7];
    const float* bnb = (const float*)d_in[8];
    const float* bw1 = (const float*)d_in[9];
    const float* bb1 = (const float*)d_in[10];
    const float* bw2 = (const float*)d_in[11];
    const float* bb2 = (const float*)d_in[12];
    const float* bg  = (const float*)d_in[13];
    const float* fnw = (const float*)d_in[14];
    const float* fnb = (const float*)d_in[15];
    const float* hw  = (const float*)d_in[16];
    const float* hb  = (const float*)d_in[17];
    const float* win = (const float*)d_in[18];

    char* ws = (char*)d_ws;
    // region A: [0, 50.3MB): xbuf fp32 + ybuf_h fp16; melTp transiently at base (dead
    // once embed GEMM writes xbuf); S_h overlays later
    float* xbuf   = (float*)ws;
    f16*   melTp  = (f16*)ws;                     // 6,309,888 B, dead after k_expand
    f16*   ybuf_h = (f16*)(ws + 33554432);
    f16*   S_h    = (f16*)ws;
    // region R: [50.3MB, 134.2MB): A_h / obuf / frames_h at base; hbuf_h at +33.5MB
    char* R = ws + 50331648;
    f16*   hbuf_h = (f16*)(R + 33554432);
    f16*   A_h    = (f16*)R;
    float* obuf   = (float*)R;
    f16*   frames_h = (f16*)R;
    // region W: [134.2MB, ...): converted weights (r6-proven envelope)
    char* Wr = ws + 134217728;
    f16*   w1_h   = (f16*)Wr;                     // 12,582,912
    f16*   w2_h   = (f16*)(Wr + 12582912);        // 12,582,912
    f16*   head_h = (f16*)(Wr + 25165824);        // 1,179,648
    f16*   wmat_h = (f16*)(Wr + 26345472);        // 2,228,224
    f16*   we_h   = (f16*)(Wr + 28573696);        // 1,376,256
    float* hb_pad = (float*)(Wr + 29949952);      // 4,608
    float* dwT    = (float*)(Wr + 29954560);      // 114,688

    const int nW1 = 8 * H_ * D_;
    k_cvt<<<(nW1 + 255) / 256, 256, 0, stream>>>(bw1, w1_h, nW1);
    k_cvt<<<(nW1 + 255) / 256, 256, 0, stream>>>(bw2, w2_h, nW1);
    k_cvt_embed<<<(D_ * KE_ + 255) / 256, 256, 0, stream>>>(embed_w, we_h);
    k_cvt_head<<<(NPAD_ * D_ + 255) / 256, 256, 0, stream>>>(hw, head_h);
    k_pad_hb<<<5, 256, 0, stream>>>(hb, hb_pad);
    k_cvtdw<<<(8 * 3584 + 255) / 256, 256, 0, stream>>>(bdw, dwT);
    k_build_wmat<<<(NFFT_ * KI_ + 255) / 256, 256, 0, stream>>>(wmat_h);

    // embed conv: mel -> melTp (fp16 t-major) -> A_h (im2col via contiguous row copies)
    k_melT<<<(B_ * TP_ * 24 + 255) / 256, 256, 0, stream>>>(mel, melTp);
    k_expand<<<(BT_ * 168 + 255) / 256, 256, 0, stream>>>(melTp, A_h);
    k_hgemm5<0><<<128 * 4, 256, 0, stream>>>(A_h, we_h, embed_b, nullptr, xbuf,
                                             KE_, D_, 4);
    k_ln<false><<<BT_, 64, 0, stream>>>(xbuf, xbuf, norm_w, norm_b);

    for (int bl = 0; bl < 8; ++bl) {
        k_dwln2<<<B_ * 128, 256, 0, stream>>>(xbuf, dwT + bl * 3584, bdb + bl * D_,
                                              bnw + bl * D_, bnb + bl * D_, ybuf_h);
        k_hgemm5<1><<<128 * 12, 256, 0, stream>>>(ybuf_h, w1_h + (size_t)bl * H_ * D_,
                                                  bb1 + bl * H_, nullptr, hbuf_h,
                                                  D_, H_, 12);
        k_hgemm5<2><<<128 * 4, 256, 0, stream>>>(hbuf_h, w2_h + (size_t)bl * D_ * H_,
                                                 bb2 + bl * D_, bg + bl * D_, xbuf,
                                                 H_, D_, 4);
    }

    k_ln<true><<<BT_, 64, 0, stream>>>(xbuf, ybuf_h, fnw, fnb);
    k_hgemm5<0><<<128 * 9, 256, 0, stream>>>(ybuf_h, head_h, hb_pad, nullptr, obuf,
                                             D_, NPAD_, 9);
    k_srsi<<<(BT_ * KI_ + 255) / 256, 256, 0, stream>>>(obuf, S_h);
    k_hgemm5<3><<<128 * 8, 256, 0, stream>>>(S_h, wmat_h, win, nullptr, frames_h,
                                             KI_, NFFT_, 8);
    k_gather<<<B_ * LOUT_ / 256, 256, 0, stream>>>(frames_h, win, (float*)d_out);
}